// Round 1
// baseline (644.192 us; speedup 1.0000x reference)
//
#include <hip/hip_runtime.h>
#include <math.h>

// Problem sizes (fixed)
#define BB 8
#define NC_ 384
#define NG 6
#define GC_ 64
#define NH 12
#define HC_ 32
#define NQ 1024                      // 32*32 queries per batch
#define NPOS_ELEMS (BB*NQ*NC_)       // 3,145,728 floats per [B,1024,384] buffer

// =====================================================================
// GEMM: C[M,N] = A[M,K] @ B[K,N] + bias[N].  M%64==0, N%64==0, K%16==0.
// BM=BN=64, BK=16, 256 threads, 4x4 micro-tile.
// =====================================================================
__global__ __launch_bounds__(256) void gemm_bias_k(
    const float* __restrict__ A, const float* __restrict__ Bw,
    const float* __restrict__ bias, float* __restrict__ C,
    int M, int N, int K)
{
    __shared__ float As[16][68];   // [k][m], padded (68 floats -> 16B-aligned rows)
    __shared__ float Bs[16][68];   // [k][n]
    const int m0 = blockIdx.x * 64;
    const int n0 = blockIdx.y * 64;
    const int tid = threadIdx.x;
    const int tm = tid >> 4, tn = tid & 15;

    float acc[4][4];
#pragma unroll
    for (int i = 0; i < 4; ++i)
#pragma unroll
        for (int j = 0; j < 4; ++j) acc[i][j] = 0.f;

    const int a_m = (tid * 4) >> 4;   // 0..63
    const int a_k = (tid * 4) & 15;   // 0,4,8,12
    const int b_k = (tid * 4) >> 6;   // 0..15
    const int b_n = (tid * 4) & 63;   // 0..60

    for (int k0 = 0; k0 < K; k0 += 16) {
        float4 av = *(const float4*)&A[(size_t)(m0 + a_m) * K + k0 + a_k];
        float4 bv = *(const float4*)&Bw[(size_t)(k0 + b_k) * N + n0 + b_n];
        As[a_k + 0][a_m] = av.x;
        As[a_k + 1][a_m] = av.y;
        As[a_k + 2][a_m] = av.z;
        As[a_k + 3][a_m] = av.w;
        *(float4*)&Bs[b_k][b_n] = bv;
        __syncthreads();
#pragma unroll
        for (int kk = 0; kk < 16; ++kk) {
            float4 a4 = *(const float4*)&As[kk][tm * 4];
            float4 b4 = *(const float4*)&Bs[kk][tn * 4];
            float a[4] = {a4.x, a4.y, a4.z, a4.w};
            float b[4] = {b4.x, b4.y, b4.z, b4.w};
#pragma unroll
            for (int i = 0; i < 4; ++i)
#pragma unroll
                for (int j = 0; j < 4; ++j)
                    acc[i][j] = fmaf(a[i], b[j], acc[i][j]);
        }
        __syncthreads();
    }

    float4 bv4 = *(const float4*)&bias[n0 + tn * 4];
#pragma unroll
    for (int i = 0; i < 4; ++i) {
        int row = m0 + tm * 4 + i;
        float4 out;
        out.x = acc[i][0] + bv4.x;
        out.y = acc[i][1] + bv4.y;
        out.z = acc[i][2] + bv4.z;
        out.w = acc[i][3] + bv4.w;
        *(float4*)&C[(size_t)row * N + n0 + tn * 4] = out;
    }
}

// =====================================================================
// Grouped 3x3 conv (SAME, zero pad), HWIO weights [3,3,64,384], groups=6.
// block = (g, y, b); 256 threads: lane = out-channel-in-group, wave = col octet.
// =====================================================================
__global__ __launch_bounds__(256) void conv_off_k(
    const float* __restrict__ q, const float* __restrict__ w,
    const float* __restrict__ bias, float* __restrict__ t)
{
    const int bid = blockIdx.x;
    const int g = bid % NG;
    const int y = (bid / NG) % 32;
    const int b = bid / (NG * 32);

    __shared__ float qs[3][34][64];   // rows y-1..y+1, cols -1..32, group channels
    __shared__ float ws[64][64];      // one tap: [ic][oc]

    const int tid = threadIdx.x;
    const int lane = tid & 63;        // oc within group
    const int wid = tid >> 6;         // 0..3 -> cols wid*8 .. wid*8+7

    for (int p = wid; p < 102; p += 4) {
        int r = p / 34, c = p % 34;
        int yy = y + r - 1, xx = c - 1;
        float vq = 0.f;
        if (yy >= 0 && yy < 32 && xx >= 0 && xx < 32)
            vq = q[(size_t)(((b * 32 + yy) * 32 + xx)) * NC_ + g * GC_ + lane];
        qs[r][c][lane] = vq;
    }

    float acc[8];
    const float bval = bias[g * GC_ + lane];
#pragma unroll
    for (int i = 0; i < 8; ++i) acc[i] = bval;

    for (int tap = 0; tap < 9; ++tap) {
        __syncthreads();
        for (int e = tid; e < 4096; e += 256) {
            int ic = e >> 6, oc = e & 63;
            ws[ic][oc] = w[(size_t)(tap * 64 + ic) * NC_ + g * GC_ + oc];
        }
        __syncthreads();
        const int kh = tap / 3, kw = tap % 3;
#pragma unroll 4
        for (int ic4 = 0; ic4 < 64; ic4 += 4) {
            float w0 = ws[ic4 + 0][lane];
            float w1 = ws[ic4 + 1][lane];
            float w2 = ws[ic4 + 2][lane];
            float w3 = ws[ic4 + 3][lane];
#pragma unroll
            for (int i = 0; i < 8; ++i) {
                float4 qv = *(const float4*)&qs[kh][wid * 8 + i + kw][ic4];
                acc[i] = fmaf(qv.x, w0, acc[i]);
                acc[i] = fmaf(qv.y, w1, acc[i]);
                acc[i] = fmaf(qv.z, w2, acc[i]);
                acc[i] = fmaf(qv.w, w3, acc[i]);
            }
        }
    }
#pragma unroll
    for (int i = 0; i < 8; ++i) {
        int x = wid * 8 + i;
        t[(size_t)(((b * 32 + y) * 32 + x)) * NC_ + g * GC_ + lane] = acc[i];
    }
}

// =====================================================================
// LayerNorm(384) + erf-GELU + per-group 64->2 projection + tanh*16 + ref
// -> warp coords [B*G, 1024, 2] as (x, y).
// One block per spatial position; 384 threads (6 waves == 6 groups).
// =====================================================================
__global__ __launch_bounds__(384) void ln_gelu_off_k(
    const float* __restrict__ t, const float* __restrict__ ln_g,
    const float* __restrict__ ln_b, const float* __restrict__ w_offp,
    float* __restrict__ warp)
{
    const int p = blockIdx.x;         // (b*32+i)*32+j
    const int c = threadIdx.x;        // channel 0..383
    const int lane = c & 63;          // ic within group
    const int wv = c >> 6;            // group

    __shared__ float red[8];
    float v = t[(size_t)p * NC_ + c];

    float s = v;
#pragma unroll
    for (int o = 32; o > 0; o >>= 1) s += __shfl_down(s, o, 64);
    if (lane == 0) red[wv] = s;
    __syncthreads();
    float mu = (red[0] + red[1] + red[2] + red[3] + red[4] + red[5]) * (1.f / 384.f);
    __syncthreads();

    float d = v - mu;
    s = d * d;
#pragma unroll
    for (int o = 32; o > 0; o >>= 1) s += __shfl_down(s, o, 64);
    if (lane == 0) red[wv] = s;
    __syncthreads();
    float var = (red[0] + red[1] + red[2] + red[3] + red[4] + red[5]) * (1.f / 384.f);

    float nv = (v - mu) * rsqrtf(var + 1e-3f) * ln_g[c] + ln_b[c];
    float gv = 0.5f * nv * (1.0f + erff(nv * 0.70710678118654752440f));

    float s0 = gv * w_offp[lane * 2 + 0];
    float s1 = gv * w_offp[lane * 2 + 1];
#pragma unroll
    for (int o = 32; o > 0; o >>= 1) {
        s0 += __shfl_down(s0, o, 64);
        s1 += __shfl_down(s1, o, 64);
    }
    if (lane == 0) {
        int b = p >> 10, ij = p & 1023;
        int i = ij >> 5, j = ij & 31;
        float off0 = tanhf(s0) * 16.0f;   // pairs with ref0 = j
        float off1 = tanhf(s1) * 16.0f;   // pairs with ref1 = i
        float px = off1 + (float)i;       // warp x
        float py = off0 + (float)j;       // warp y
        int bg = b * NG + wv;
        warp[((size_t)bg * NQ + ij) * 2 + 0] = px;
        warp[((size_t)bg * NQ + ij) * 2 + 1] = py;
    }
}

// =====================================================================
// Bilinear sampling with zero border (faithful to reference clip/floor).
// One thread per (bg, q, 4-channel chunk). Writes xs[B,1024,384].
// =====================================================================
__device__ inline float4 tap_load(const float* __restrict__ x, int b, int g,
                                  int yp, int xp, int ic4)
{
    int r = yp - 1, c = xp - 1;   // padded -> original coords
    if ((unsigned)r < 32u && (unsigned)c < 32u)
        return *(const float4*)&x[(size_t)(((b * 32 + r) * 32 + c)) * NC_ + g * GC_ + ic4];
    return make_float4(0.f, 0.f, 0.f, 0.f);
}

__global__ __launch_bounds__(256) void sample_kk(
    const float* __restrict__ x, const float* __restrict__ warp,
    float* __restrict__ xs)
{
    const int gidx = blockIdx.x * 256 + threadIdx.x;  // < 48*1024*16
    const int ic4 = (gidx & 15) * 4;
    const int qq = (gidx >> 4) & 1023;
    const int bg = gidx >> 14;
    const int b = bg / NG, g = bg % NG;

    const float wx = warp[((size_t)bg * NQ + qq) * 2 + 0];
    const float wy = warp[((size_t)bg * NQ + qq) * 2 + 1];
    const float xq = wx + 1.0f, yq = wy + 1.0f;
    float x0 = fminf(fmaxf(floorf(xq), 0.f), 32.f);
    float y0 = fminf(fmaxf(floorf(yq), 0.f), 32.f);
    float ax = fminf(fmaxf(xq - x0, 0.f), 1.f);
    float ay = fminf(fmaxf(yq - y0, 0.f), 1.f);
    int xi = (int)x0, yi = (int)y0;

    float4 tl = tap_load(x, b, g, yi,     xi,     ic4);
    float4 tr = tap_load(x, b, g, yi,     xi + 1, ic4);
    float4 bl = tap_load(x, b, g, yi + 1, xi,     ic4);
    float4 br = tap_load(x, b, g, yi + 1, xi + 1, ic4);

    float4 top, bot, r;
    top.x = tl.x + ax * (tr.x - tl.x); top.y = tl.y + ax * (tr.y - tl.y);
    top.z = tl.z + ax * (tr.z - tl.z); top.w = tl.w + ax * (tr.w - tl.w);
    bot.x = bl.x + ax * (br.x - bl.x); bot.y = bl.y + ax * (br.y - bl.y);
    bot.z = bl.z + ax * (br.z - bl.z); bot.w = bl.w + ax * (br.w - bl.w);
    r.x = top.x + ay * (bot.x - top.x); r.y = top.y + ay * (bot.y - top.y);
    r.z = top.z + ay * (bot.z - top.z); r.w = top.w + ay * (bot.w - top.w);

    *(float4*)&xs[((size_t)b * NQ + qq) * NC_ + g * GC_ + ic4] = r;
}

// =====================================================================
// Flash-style attention: per block (mt, b*12+h); 64-query tile, 12 heads,
// HC=32, 1024 keys in 16 tiles of 64. fp32, online softmax.
// =====================================================================
__global__ __launch_bounds__(256) void attn_k(
    const float* __restrict__ q, const float* __restrict__ k,
    const float* __restrict__ v, float* __restrict__ o)
{
    __shared__ float Qs[64][36];
    __shared__ float Ks[64][36];
    __shared__ float Vs[64][36];
    __shared__ float Ps[64][68];

    const int mt = blockIdx.x;          // 0..15
    const int bh = blockIdx.y;          // 0..95
    const int b = bh / NH, h = bh % NH;
    const int tid = threadIdx.x;
    const int tm = tid >> 4, tn = tid & 15;
    const int lr = tid >> 2;            // load row 0..63
    const int lc = (tid & 3) * 8;       // load col 0,8,16,24
    const float scale = 0.17677669529663687f;   // 32^-0.5

    {
        size_t baseq = ((size_t)b * NQ + mt * 64 + lr) * NC_ + h * HC_ + lc;
        float4 q0 = *(const float4*)&q[baseq];
        float4 q1 = *(const float4*)&q[baseq + 4];
        q0.x *= scale; q0.y *= scale; q0.z *= scale; q0.w *= scale;
        q1.x *= scale; q1.y *= scale; q1.z *= scale; q1.w *= scale;
        *(float4*)&Qs[lr][lc] = q0;
        *(float4*)&Qs[lr][lc + 4] = q1;
    }

    float m_i[4], l_i[4], oa[4][2];
#pragma unroll
    for (int i = 0; i < 4; ++i) {
        m_i[i] = -INFINITY; l_i[i] = 0.f;
        oa[i][0] = 0.f; oa[i][1] = 0.f;
    }

    for (int n0 = 0; n0 < NQ; n0 += 64) {
        __syncthreads();   // previous iteration's readers done
        {
            size_t basek = ((size_t)b * NQ + n0 + lr) * NC_ + h * HC_ + lc;
            *(float4*)&Ks[lr][lc]     = *(const float4*)&k[basek];
            *(float4*)&Ks[lr][lc + 4] = *(const float4*)&k[basek + 4];
            *(float4*)&Vs[lr][lc]     = *(const float4*)&v[basek];
            *(float4*)&Vs[lr][lc + 4] = *(const float4*)&v[basek + 4];
        }
        __syncthreads();

        // S = Qtile @ Ktile^T (scaled)
        float sa[4][4];
#pragma unroll
        for (int i = 0; i < 4; ++i)
#pragma unroll
            for (int j = 0; j < 4; ++j) sa[i][j] = 0.f;

#pragma unroll
        for (int c4 = 0; c4 < HC_; c4 += 4) {
            float4 a[4], bb[4];
#pragma unroll
            for (int i = 0; i < 4; ++i) a[i] = *(const float4*)&Qs[tm * 4 + i][c4];
#pragma unroll
            for (int j = 0; j < 4; ++j) bb[j] = *(const float4*)&Ks[tn * 4 + j][c4];
#pragma unroll
            for (int i = 0; i < 4; ++i)
#pragma unroll
                for (int j = 0; j < 4; ++j) {
                    sa[i][j] = fmaf(a[i].x, bb[j].x, sa[i][j]);
                    sa[i][j] = fmaf(a[i].y, bb[j].y, sa[i][j]);
                    sa[i][j] = fmaf(a[i].z, bb[j].z, sa[i][j]);
                    sa[i][j] = fmaf(a[i].w, bb[j].w, sa[i][j]);
                }
        }

        // online softmax update (rows tm*4..tm*4+3; 16-thread row groups)
#pragma unroll
        for (int i = 0; i < 4; ++i) {
            float mx = fmaxf(fmaxf(sa[i][0], sa[i][1]), fmaxf(sa[i][2], sa[i][3]));
            mx = fmaxf(mx, __shfl_xor(mx, 1, 16));
            mx = fmaxf(mx, __shfl_xor(mx, 2, 16));
            mx = fmaxf(mx, __shfl_xor(mx, 4, 16));
            mx = fmaxf(mx, __shfl_xor(mx, 8, 16));
            float mn = fmaxf(m_i[i], mx);
            float al = __expf(m_i[i] - mn);
            float p0 = __expf(sa[i][0] - mn);
            float p1 = __expf(sa[i][1] - mn);
            float p2 = __expf(sa[i][2] - mn);
            float p3 = __expf(sa[i][3] - mn);
            float rs = p0 + p1 + p2 + p3;
            rs += __shfl_xor(rs, 1, 16);
            rs += __shfl_xor(rs, 2, 16);
            rs += __shfl_xor(rs, 4, 16);
            rs += __shfl_xor(rs, 8, 16);
            l_i[i] = l_i[i] * al + rs;
            m_i[i] = mn;
            oa[i][0] *= al; oa[i][1] *= al;
            *(float4*)&Ps[tm * 4 + i][tn * 4] = make_float4(p0, p1, p2, p3);
        }
        __syncthreads();

        // O += P @ Vtile   (rows tm*4.., cols tn*2 + {0,1})
#pragma unroll
        for (int n4 = 0; n4 < 64; n4 += 4) {
            float pr[4][4];
#pragma unroll
            for (int i = 0; i < 4; ++i)
                *(float4*)&pr[i][0] = *(const float4*)&Ps[tm * 4 + i][n4];
#pragma unroll
            for (int u = 0; u < 4; ++u) {
                float v0 = Vs[n4 + u][tn * 2 + 0];
                float v1 = Vs[n4 + u][tn * 2 + 1];
#pragma unroll
                for (int i = 0; i < 4; ++i) {
                    oa[i][0] = fmaf(pr[i][u], v0, oa[i][0]);
                    oa[i][1] = fmaf(pr[i][u], v1, oa[i][1]);
                }
            }
        }
    }

    size_t baseo = ((size_t)b * NQ + mt * 64) * NC_ + h * HC_;
#pragma unroll
    for (int i = 0; i < 4; ++i) {
        float inv = 1.f / l_i[i];
        o[baseo + (size_t)(tm * 4 + i) * NC_ + tn * 2 + 0] = oa[i][0] * inv;
        o[baseo + (size_t)(tm * 4 + i) * NC_ + tn * 2 + 1] = oa[i][1] * inv;
    }
}

// =====================================================================
// Launch. Workspace layout (floats): q | t(=attn-out) | xs | k | v | warp
// Total: 5*3,145,728 + 98,304 floats = 63.4 MB.
// =====================================================================
extern "C" void kernel_launch(void* const* d_in, const int* in_sizes, int n_in,
                              void* d_out, int out_size, void* d_ws, size_t ws_size,
                              hipStream_t stream)
{
    const float* x      = (const float*)d_in[0];
    const float* w_q    = (const float*)d_in[1];
    const float* b_q    = (const float*)d_in[2];
    const float* w_off0 = (const float*)d_in[3];
    const float* b_off0 = (const float*)d_in[4];
    const float* ln_g   = (const float*)d_in[5];
    const float* ln_b   = (const float*)d_in[6];
    const float* w_offp = (const float*)d_in[7];
    const float* w_k    = (const float*)d_in[8];
    const float* b_k    = (const float*)d_in[9];
    const float* w_v    = (const float*)d_in[10];
    const float* b_v    = (const float*)d_in[11];
    const float* w_o    = (const float*)d_in[12];
    const float* b_o    = (const float*)d_in[13];

    float* ws = (float*)d_ws;
    float* q   = ws;
    float* t   = ws + (size_t)NPOS_ELEMS;       // reused as attention output
    float* xs  = ws + (size_t)2 * NPOS_ELEMS;
    float* kb  = ws + (size_t)3 * NPOS_ELEMS;
    float* vb  = ws + (size_t)4 * NPOS_ELEMS;
    float* wp  = ws + (size_t)5 * NPOS_ELEMS;   // warp coords: 98,304 floats

    const int M = BB * NQ;   // 8192

    gemm_bias_k<<<dim3(M / 64, NC_ / 64), 256, 0, stream>>>(x, w_q, b_q, q, M, NC_, NC_);
    conv_off_k<<<BB * 32 * NG, 256, 0, stream>>>(q, w_off0, b_off0, t);
    ln_gelu_off_k<<<M, 384, 0, stream>>>(t, ln_g, ln_b, w_offp, wp);
    sample_kk<<<(BB * NG * NQ * 16) / 256, 256, 0, stream>>>(x, wp, xs);
    gemm_bias_k<<<dim3(M / 64, NC_ / 64), 256, 0, stream>>>(xs, w_k, b_k, kb, M, NC_, NC_);
    gemm_bias_k<<<dim3(M / 64, NC_ / 64), 256, 0, stream>>>(xs, w_v, b_v, vb, M, NC_, NC_);
    attn_k<<<dim3(NQ / 64, BB * NH), 256, 0, stream>>>(q, kb, vb, t);
    gemm_bias_k<<<dim3(M / 64, NC_ / 64), 256, 0, stream>>>(t, w_o, b_o, (float*)d_out, M, NC_, NC_);
}

// Round 2
// 469.523 us; speedup vs baseline: 1.3720x; 1.3720x over previous
//
#include <hip/hip_runtime.h>
#include <math.h>

// Problem sizes (fixed)
#define BB 8
#define NC_ 384
#define NG 6
#define GC_ 64
#define NH 12
#define HC_ 32
#define NQ 1024                      // 32*32 queries per batch
#define NPOS_ELEMS (BB*NQ*NC_)       // 3,145,728 floats per [B,1024,384] buffer

typedef short bf16x8 __attribute__((ext_vector_type(8)));
typedef float f32x4  __attribute__((ext_vector_type(4)));

__device__ inline ushort f2bf(float f) {
    union { float f; unsigned u; } v; v.f = f;
    unsigned r = v.u + 0x7FFFu + ((v.u >> 16) & 1u);   // RNE
    return (ushort)(r >> 16);
}

__device__ inline bf16x8 pack8(const float* f) {
    bf16x8 r;
#pragma unroll
    for (int i = 0; i < 8; ++i) r[i] = (short)f2bf(f[i]);
    return r;
}

// =====================================================================
// GEMM: C[M,N] = A[M,K] @ B[K,N] + bias[N].  Template: fp32 or bf16 out.
// BM=BN=64, BK=16, 256 threads, 4x4 micro-tile.
// =====================================================================
template<int OUT_BF16>
__global__ __launch_bounds__(256) void gemm_bias_k(
    const float* __restrict__ A, const float* __restrict__ Bw,
    const float* __restrict__ bias, void* __restrict__ Cv,
    int M, int N, int K)
{
    __shared__ float As[16][68];
    __shared__ float Bs[16][68];
    const int m0 = blockIdx.x * 64;
    const int n0 = blockIdx.y * 64;
    const int tid = threadIdx.x;
    const int tm = tid >> 4, tn = tid & 15;

    float acc[4][4];
#pragma unroll
    for (int i = 0; i < 4; ++i)
#pragma unroll
        for (int j = 0; j < 4; ++j) acc[i][j] = 0.f;

    const int a_m = (tid * 4) >> 4;
    const int a_k = (tid * 4) & 15;
    const int b_k = (tid * 4) >> 6;
    const int b_n = (tid * 4) & 63;

    for (int k0 = 0; k0 < K; k0 += 16) {
        float4 av = *(const float4*)&A[(size_t)(m0 + a_m) * K + k0 + a_k];
        float4 bv = *(const float4*)&Bw[(size_t)(k0 + b_k) * N + n0 + b_n];
        As[a_k + 0][a_m] = av.x;
        As[a_k + 1][a_m] = av.y;
        As[a_k + 2][a_m] = av.z;
        As[a_k + 3][a_m] = av.w;
        *(float4*)&Bs[b_k][b_n] = bv;
        __syncthreads();
#pragma unroll
        for (int kk = 0; kk < 16; ++kk) {
            float4 a4 = *(const float4*)&As[kk][tm * 4];
            float4 b4 = *(const float4*)&Bs[kk][tn * 4];
            float a[4] = {a4.x, a4.y, a4.z, a4.w};
            float b[4] = {b4.x, b4.y, b4.z, b4.w};
#pragma unroll
            for (int i = 0; i < 4; ++i)
#pragma unroll
                for (int j = 0; j < 4; ++j)
                    acc[i][j] = fmaf(a[i], b[j], acc[i][j]);
        }
        __syncthreads();
    }

    float4 bv4 = *(const float4*)&bias[n0 + tn * 4];
#pragma unroll
    for (int i = 0; i < 4; ++i) {
        int row = m0 + tm * 4 + i;
        float o0 = acc[i][0] + bv4.x;
        float o1 = acc[i][1] + bv4.y;
        float o2 = acc[i][2] + bv4.z;
        float o3 = acc[i][3] + bv4.w;
        if constexpr (OUT_BF16) {
            ushort4 ov;
            ov.x = f2bf(o0); ov.y = f2bf(o1); ov.z = f2bf(o2); ov.w = f2bf(o3);
            *(ushort4*)&((ushort*)Cv)[(size_t)row * N + n0 + tn * 4] = ov;
        } else {
            float4 ov = make_float4(o0, o1, o2, o3);
            *(float4*)&((float*)Cv)[(size_t)row * N + n0 + tn * 4] = ov;
        }
    }
}

// =====================================================================
// Grouped 3x3 conv (SAME, zero pad), HWIO weights [3,3,64,384], groups=6.
// =====================================================================
__global__ __launch_bounds__(256) void conv_off_k(
    const float* __restrict__ q, const float* __restrict__ w,
    const float* __restrict__ bias, float* __restrict__ t)
{
    const int bid = blockIdx.x;
    const int g = bid % NG;
    const int y = (bid / NG) % 32;
    const int b = bid / (NG * 32);

    __shared__ float qs[3][34][64];
    __shared__ float ws[64][64];

    const int tid = threadIdx.x;
    const int lane = tid & 63;
    const int wid = tid >> 6;

    for (int p = wid; p < 102; p += 4) {
        int r = p / 34, c = p % 34;
        int yy = y + r - 1, xx = c - 1;
        float vq = 0.f;
        if (yy >= 0 && yy < 32 && xx >= 0 && xx < 32)
            vq = q[(size_t)(((b * 32 + yy) * 32 + xx)) * NC_ + g * GC_ + lane];
        qs[r][c][lane] = vq;
    }

    float acc[8];
    const float bval = bias[g * GC_ + lane];
#pragma unroll
    for (int i = 0; i < 8; ++i) acc[i] = bval;

    for (int tap = 0; tap < 9; ++tap) {
        __syncthreads();
        for (int e = tid; e < 4096; e += 256) {
            int ic = e >> 6, oc = e & 63;
            ws[ic][oc] = w[(size_t)(tap * 64 + ic) * NC_ + g * GC_ + oc];
        }
        __syncthreads();
        const int kh = tap / 3, kw = tap % 3;
#pragma unroll 4
        for (int ic4 = 0; ic4 < 64; ic4 += 4) {
            float w0 = ws[ic4 + 0][lane];
            float w1 = ws[ic4 + 1][lane];
            float w2 = ws[ic4 + 2][lane];
            float w3 = ws[ic4 + 3][lane];
#pragma unroll
            for (int i = 0; i < 8; ++i) {
                float4 qv = *(const float4*)&qs[kh][wid * 8 + i + kw][ic4];
                acc[i] = fmaf(qv.x, w0, acc[i]);
                acc[i] = fmaf(qv.y, w1, acc[i]);
                acc[i] = fmaf(qv.z, w2, acc[i]);
                acc[i] = fmaf(qv.w, w3, acc[i]);
            }
        }
    }
#pragma unroll
    for (int i = 0; i < 8; ++i) {
        int x = wid * 8 + i;
        t[(size_t)(((b * 32 + y) * 32 + x)) * NC_ + g * GC_ + lane] = acc[i];
    }
}

// =====================================================================
// LayerNorm(384) + erf-GELU + per-group 64->2 proj + tanh*16 + ref grid.
// =====================================================================
__global__ __launch_bounds__(384) void ln_gelu_off_k(
    const float* __restrict__ t, const float* __restrict__ ln_g,
    const float* __restrict__ ln_b, const float* __restrict__ w_offp,
    float* __restrict__ warp)
{
    const int p = blockIdx.x;
    const int c = threadIdx.x;
    const int lane = c & 63;
    const int wv = c >> 6;

    __shared__ float red[8];
    float v = t[(size_t)p * NC_ + c];

    float s = v;
#pragma unroll
    for (int o = 32; o > 0; o >>= 1) s += __shfl_down(s, o, 64);
    if (lane == 0) red[wv] = s;
    __syncthreads();
    float mu = (red[0] + red[1] + red[2] + red[3] + red[4] + red[5]) * (1.f / 384.f);
    __syncthreads();

    float d = v - mu;
    s = d * d;
#pragma unroll
    for (int o = 32; o > 0; o >>= 1) s += __shfl_down(s, o, 64);
    if (lane == 0) red[wv] = s;
    __syncthreads();
    float var = (red[0] + red[1] + red[2] + red[3] + red[4] + red[5]) * (1.f / 384.f);

    float nv = (v - mu) * rsqrtf(var + 1e-3f) * ln_g[c] + ln_b[c];
    float gv = 0.5f * nv * (1.0f + erff(nv * 0.70710678118654752440f));

    float s0 = gv * w_offp[lane * 2 + 0];
    float s1 = gv * w_offp[lane * 2 + 1];
#pragma unroll
    for (int o = 32; o > 0; o >>= 1) {
        s0 += __shfl_down(s0, o, 64);
        s1 += __shfl_down(s1, o, 64);
    }
    if (lane == 0) {
        int b = p >> 10, ij = p & 1023;
        int i = ij >> 5, j = ij & 31;
        float off0 = tanhf(s0) * 16.0f;
        float off1 = tanhf(s1) * 16.0f;
        float px = off1 + (float)i;
        float py = off0 + (float)j;
        int bg = b * NG + wv;
        warp[((size_t)bg * NQ + ij) * 2 + 0] = px;
        warp[((size_t)bg * NQ + ij) * 2 + 1] = py;
    }
}

// =====================================================================
// Bilinear sampling with zero border.
// =====================================================================
__device__ inline float4 tap_load(const float* __restrict__ x, int b, int g,
                                  int yp, int xp, int ic4)
{
    int r = yp - 1, c = xp - 1;
    if ((unsigned)r < 32u && (unsigned)c < 32u)
        return *(const float4*)&x[(size_t)(((b * 32 + r) * 32 + c)) * NC_ + g * GC_ + ic4];
    return make_float4(0.f, 0.f, 0.f, 0.f);
}

__global__ __launch_bounds__(256) void sample_kk(
    const float* __restrict__ x, const float* __restrict__ warp,
    float* __restrict__ xs)
{
    const int gidx = blockIdx.x * 256 + threadIdx.x;
    const int ic4 = (gidx & 15) * 4;
    const int qq = (gidx >> 4) & 1023;
    const int bg = gidx >> 14;
    const int b = bg / NG, g = bg % NG;

    const float wx = warp[((size_t)bg * NQ + qq) * 2 + 0];
    const float wy = warp[((size_t)bg * NQ + qq) * 2 + 1];
    const float xq = wx + 1.0f, yq = wy + 1.0f;
    float x0 = fminf(fmaxf(floorf(xq), 0.f), 32.f);
    float y0 = fminf(fmaxf(floorf(yq), 0.f), 32.f);
    float ax = fminf(fmaxf(xq - x0, 0.f), 1.f);
    float ay = fminf(fmaxf(yq - y0, 0.f), 1.f);
    int xi = (int)x0, yi = (int)y0;

    float4 tl = tap_load(x, b, g, yi,     xi,     ic4);
    float4 tr = tap_load(x, b, g, yi,     xi + 1, ic4);
    float4 bl = tap_load(x, b, g, yi + 1, xi,     ic4);
    float4 br = tap_load(x, b, g, yi + 1, xi + 1, ic4);

    float4 top, bot, r;
    top.x = tl.x + ax * (tr.x - tl.x); top.y = tl.y + ax * (tr.y - tl.y);
    top.z = tl.z + ax * (tr.z - tl.z); top.w = tl.w + ax * (tr.w - tl.w);
    bot.x = bl.x + ax * (br.x - bl.x); bot.y = bl.y + ax * (br.y - bl.y);
    bot.z = bl.z + ax * (br.z - bl.z); bot.w = bl.w + ax * (br.w - bl.w);
    r.x = top.x + ay * (bot.x - top.x); r.y = top.y + ay * (bot.y - top.y);
    r.z = top.z + ay * (bot.z - top.z); r.w = top.w + ay * (bot.w - top.w);

    *(float4*)&xs[((size_t)b * NQ + qq) * NC_ + g * GC_ + ic4] = r;
}

// =====================================================================
// MFMA flash attention (bf16 inputs, fp32 accum).
// Block = 64 queries of one (b,h); 4 waves x 16 queries. 16 key-tiles of 64.
// K frags loaded straight from global bf16 (L2-resident). V staged transposed
// into XOR-swizzled LDS once per block per tile. P bounced through per-wave
// XOR-swizzled LDS. Fragment k-mapping assumed symmetric for A/B (safe);
// C/D mapping col=lane&15,row=(lane>>4)*4+reg (HW-verified).
// =====================================================================
__global__ __launch_bounds__(256) void attn_mfma_k(
    const float* __restrict__ q, const ushort* __restrict__ kb,
    const ushort* __restrict__ vb, float* __restrict__ o)
{
    __shared__ __align__(16) ushort Vt[2048];       // [32c][64k], swizzled
    __shared__ __align__(16) ushort Pl[4][1024];    // per-wave [16q][64k], swizzled

    const int mt = blockIdx.x;          // 0..15 query tile
    const int bh = blockIdx.y;          // 0..95
    const int b = bh / NH, h = bh % NH;
    const int tid = threadIdx.x;
    const int w = tid >> 6;             // wave 0..3
    const int lane = tid & 63;
    const int c15 = lane & 15;
    const int lg = lane >> 4;

    const float scale = 0.17677669529663687f;   // 32^-0.5

    // Q fragment (A operand): row c15 of wave's 16 queries, k = lg*8 + i
    bf16x8 qf;
    {
        const float* qp = &q[((size_t)b * NQ + mt * 64 + w * 16 + c15) * NC_ + h * HC_ + lg * 8];
        float tmp[8];
        *(float4*)&tmp[0] = *(const float4*)qp;
        *(float4*)&tmp[4] = *(const float4*)(qp + 4);
#pragma unroll
        for (int i = 0; i < 8; ++i) tmp[i] *= scale;
        qf = pack8(tmp);
    }

    f32x4 oacc[2];
    oacc[0] = (f32x4){0.f, 0.f, 0.f, 0.f};
    oacc[1] = (f32x4){0.f, 0.f, 0.f, 0.f};
    float m_i[4], l_i[4];
#pragma unroll
    for (int r = 0; r < 4; ++r) { m_i[r] = -INFINITY; l_i[r] = 0.f; }

    const int vc = tid >> 3;            // 0..31: channel for V staging
    const int vk8 = (tid & 7) * 8;      // k start for V staging
    const int vt_widx = (vc * 64 + vk8) ^ ((vc & 7) << 3);   // ushort index

    for (int n0 = 0; n0 < NQ; n0 += 64) {
        __syncthreads();   // previous tile's Vt readers done

        // ---- stage V tile transposed: Vt[c][k] = V[n0+k][c] ----
        {
            const ushort* vp = &vb[((size_t)b * NQ + n0 + vk8) * NC_ + h * HC_ + vc];
            bf16x8 vv;
#pragma unroll
            for (int j = 0; j < 8; ++j) vv[j] = (short)vp[(size_t)j * NC_];
            *(bf16x8*)&Vt[vt_widx] = vv;
        }

        // ---- K frags from global + S = Q.K^T MFMAs ----
        f32x4 sacc[4];
        {
            const ushort* kp = &kb[((size_t)b * NQ + n0 + c15) * NC_ + h * HC_ + lg * 8];
            const f32x4 z = (f32x4){0.f, 0.f, 0.f, 0.f};
#pragma unroll
            for (int kt = 0; kt < 4; ++kt) {
                bf16x8 kf = *(const bf16x8*)(kp + (size_t)kt * 16 * NC_);
                sacc[kt] = __builtin_amdgcn_mfma_f32_16x16x32_bf16(qf, kf, z, 0, 0, 0);
            }
        }
        __syncthreads();   // Vt ready

        // ---- online softmax (lane holds S[q=lg*4+r][key=kt*16+c15]) ----
        float pv[4][4];    // [kt][r]
#pragma unroll
        for (int r = 0; r < 4; ++r) {
            float mx = fmaxf(fmaxf(sacc[0][r], sacc[1][r]), fmaxf(sacc[2][r], sacc[3][r]));
            mx = fmaxf(mx, __shfl_xor(mx, 1, 16));
            mx = fmaxf(mx, __shfl_xor(mx, 2, 16));
            mx = fmaxf(mx, __shfl_xor(mx, 4, 16));
            mx = fmaxf(mx, __shfl_xor(mx, 8, 16));
            float mn = fmaxf(m_i[r], mx);
            float al = __expf(m_i[r] - mn);
            m_i[r] = mn;
            float p0 = __expf(sacc[0][r] - mn);
            float p1 = __expf(sacc[1][r] - mn);
            float p2 = __expf(sacc[2][r] - mn);
            float p3 = __expf(sacc[3][r] - mn);
            pv[0][r] = p0; pv[1][r] = p1; pv[2][r] = p2; pv[3][r] = p3;
            float rs = p0 + p1 + p2 + p3;
            rs += __shfl_xor(rs, 1, 16);
            rs += __shfl_xor(rs, 2, 16);
            rs += __shfl_xor(rs, 4, 16);
            rs += __shfl_xor(rs, 8, 16);
            l_i[r] = l_i[r] * al + rs;
            oacc[0][r] *= al;
            oacc[1][r] *= al;
        }

        // ---- write P to per-wave LDS (bf16, swizzled) ----
#pragma unroll
        for (int r = 0; r < 4; ++r) {
            const int qq = lg * 4 + r;
            const int sw = (qq & 7) << 3;
#pragma unroll
            for (int kt = 0; kt < 4; ++kt)
                Pl[w][qq * 64 + ((kt * 16 + c15) ^ sw)] = f2bf(pv[kt][r]);
        }

        // ---- O += P.V (A-frag: P[q=c15][k], B-frag: V[k][c]) ----
#pragma unroll
        for (int kblk = 0; kblk < 2; ++kblk) {
            bf16x8 pf = *(bf16x8*)&Pl[w][c15 * 64 + ((kblk * 32 + lg * 8) ^ ((c15 & 7) << 3))];
#pragma unroll
            for (int ct = 0; ct < 2; ++ct) {
                const int cc = ct * 16 + c15;
                bf16x8 vf = *(bf16x8*)&Vt[(cc * 64 + kblk * 32 + lg * 8) ^ ((cc & 7) << 3)];
                oacc[ct] = __builtin_amdgcn_mfma_f32_16x16x32_bf16(pf, vf, oacc[ct], 0, 0, 0);
            }
        }
    }

    // ---- store O (rows = queries lg*4+r, cols = channels ct*16+c15) ----
#pragma unroll
    for (int r = 0; r < 4; ++r) {
        float inv = 1.f / l_i[r];
        size_t row = (size_t)b * NQ + mt * 64 + w * 16 + lg * 4 + r;
        o[row * NC_ + h * HC_ + c15]      = oacc[0][r] * inv;
        o[row * NC_ + h * HC_ + 16 + c15] = oacc[1][r] * inv;
    }
}

// =====================================================================
// Launch. ws floats: q | t(=attn-out) | xs | kb(bf16) | vb(bf16) | warp
// =====================================================================
extern "C" void kernel_launch(void* const* d_in, const int* in_sizes, int n_in,
                              void* d_out, int out_size, void* d_ws, size_t ws_size,
                              hipStream_t stream)
{
    const float* x      = (const float*)d_in[0];
    const float* w_q    = (const float*)d_in[1];
    const float* b_q    = (const float*)d_in[2];
    const float* w_off0 = (const float*)d_in[3];
    const float* b_off0 = (const float*)d_in[4];
    const float* ln_g   = (const float*)d_in[5];
    const float* ln_b   = (const float*)d_in[6];
    const float* w_offp = (const float*)d_in[7];
    const float* w_k    = (const float*)d_in[8];
    const float* b_k    = (const float*)d_in[9];
    const float* w_v    = (const float*)d_in[10];
    const float* b_v    = (const float*)d_in[11];
    const float* w_o    = (const float*)d_in[12];
    const float* b_o    = (const float*)d_in[13];

    float* ws = (float*)d_ws;
    float*  q    = ws;
    float*  t    = ws + (size_t)NPOS_ELEMS;       // reused as attention output
    float*  xs   = ws + (size_t)2 * NPOS_ELEMS;
    ushort* kb16 = (ushort*)(ws + (size_t)3 * NPOS_ELEMS);
    ushort* vb16 = (ushort*)(ws + (size_t)4 * NPOS_ELEMS);
    float*  wp   = ws + (size_t)5 * NPOS_ELEMS;   // warp coords

    const int M = BB * NQ;   // 8192

    gemm_bias_k<0><<<dim3(M / 64, NC_ / 64), 256, 0, stream>>>(x, w_q, b_q, (void*)q, M, NC_, NC_);
    conv_off_k<<<BB * 32 * NG, 256, 0, stream>>>(q, w_off0, b_off0, t);
    ln_gelu_off_k<<<M, 384, 0, stream>>>(t, ln_g, ln_b, w_offp, wp);
    sample_kk<<<(BB * NG * NQ * 16) / 256, 256, 0, stream>>>(x, wp, xs);
    gemm_bias_k<1><<<dim3(M / 64, NC_ / 64), 256, 0, stream>>>(xs, w_k, b_k, (void*)kb16, M, NC_, NC_);
    gemm_bias_k<1><<<dim3(M / 64, NC_ / 64), 256, 0, stream>>>(xs, w_v, b_v, (void*)vb16, M, NC_, NC_);
    attn_mfma_k<<<dim3(NQ / 64, BB * NH), 256, 0, stream>>>(q, kb16, vb16, t);
    gemm_bias_k<0><<<dim3(M / 64, NC_ / 64), 256, 0, stream>>>(t, w_o, b_o, (void*)d_out, M, NC_, NC_);
}

// Round 3
// 390.565 us; speedup vs baseline: 1.6494x; 1.2022x over previous
//
#include <hip/hip_runtime.h>
#include <math.h>

// Problem sizes (fixed)
#define BB 8
#define NC_ 384
#define NG 6
#define GC_ 64
#define NH 12
#define HC_ 32
#define NQ 1024                      // 32*32 queries per batch
#define NPOS_ELEMS (BB*NQ*NC_)       // 3,145,728 floats per [B,1024,384] buffer
#define WT_ELEMS (NG*9*GC_*GC_)      // 221,184 per split plane

typedef short bf16x8 __attribute__((ext_vector_type(8)));
typedef float f32x4  __attribute__((ext_vector_type(4)));

__device__ inline ushort f2bf(float f) {
    union { float f; unsigned u; } v; v.f = f;
    unsigned r = v.u + 0x7FFFu + ((v.u >> 16) & 1u);   // RNE
    return (ushort)(r >> 16);
}
__device__ inline float bf2f(ushort h) {
    union { unsigned u; float f; } v; v.u = ((unsigned)h) << 16;
    return v.f;
}
__device__ inline bf16x8 pack8(const float* f) {
    bf16x8 r;
#pragma unroll
    for (int i = 0; i < 8; ++i) r[i] = (short)f2bf(f[i]);
    return r;
}

// =====================================================================
// GEMM: C[M,N] = A[M,K] @ B[K,N] + bias[N].  Template: fp32 or bf16 out.
// =====================================================================
template<int OUT_BF16>
__global__ __launch_bounds__(256) void gemm_bias_k(
    const float* __restrict__ A, const float* __restrict__ Bw,
    const float* __restrict__ bias, void* __restrict__ Cv,
    int M, int N, int K)
{
    __shared__ float As[16][68];
    __shared__ float Bs[16][68];
    const int m0 = blockIdx.x * 64;
    const int n0 = blockIdx.y * 64;
    const int tid = threadIdx.x;
    const int tm = tid >> 4, tn = tid & 15;

    float acc[4][4];
#pragma unroll
    for (int i = 0; i < 4; ++i)
#pragma unroll
        for (int j = 0; j < 4; ++j) acc[i][j] = 0.f;

    const int a_m = (tid * 4) >> 4;
    const int a_k = (tid * 4) & 15;
    const int b_k = (tid * 4) >> 6;
    const int b_n = (tid * 4) & 63;

    for (int k0 = 0; k0 < K; k0 += 16) {
        float4 av = *(const float4*)&A[(size_t)(m0 + a_m) * K + k0 + a_k];
        float4 bv = *(const float4*)&Bw[(size_t)(k0 + b_k) * N + n0 + b_n];
        As[a_k + 0][a_m] = av.x;
        As[a_k + 1][a_m] = av.y;
        As[a_k + 2][a_m] = av.z;
        As[a_k + 3][a_m] = av.w;
        *(float4*)&Bs[b_k][b_n] = bv;
        __syncthreads();
#pragma unroll
        for (int kk = 0; kk < 16; ++kk) {
            float4 a4 = *(const float4*)&As[kk][tm * 4];
            float4 b4 = *(const float4*)&Bs[kk][tn * 4];
            float a[4] = {a4.x, a4.y, a4.z, a4.w};
            float b[4] = {b4.x, b4.y, b4.z, b4.w};
#pragma unroll
            for (int i = 0; i < 4; ++i)
#pragma unroll
                for (int j = 0; j < 4; ++j)
                    acc[i][j] = fmaf(a[i], b[j], acc[i][j]);
        }
        __syncthreads();
    }

    float4 bv4 = *(const float4*)&bias[n0 + tn * 4];
#pragma unroll
    for (int i = 0; i < 4; ++i) {
        int row = m0 + tm * 4 + i;
        float o0 = acc[i][0] + bv4.x;
        float o1 = acc[i][1] + bv4.y;
        float o2 = acc[i][2] + bv4.z;
        float o3 = acc[i][3] + bv4.w;
        if constexpr (OUT_BF16) {
            ushort4 ov;
            ov.x = f2bf(o0); ov.y = f2bf(o1); ov.z = f2bf(o2); ov.w = f2bf(o3);
            *(ushort4*)&((ushort*)Cv)[(size_t)row * N + n0 + tn * 4] = ov;
        } else {
            float4 ov = make_float4(o0, o1, o2, o3);
            *(float4*)&((float*)Cv)[(size_t)row * N + n0 + tn * 4] = ov;
        }
    }
}

// =====================================================================
// Weight transpose + split for conv: w_off0 [3,3,64,384] (HWIO) ->
// wt[plane][g][tap][oc][ic] bf16, plane 0 = hi, plane 1 = lo.
// =====================================================================
__global__ __launch_bounds__(256) void wconv_t_k(
    const float* __restrict__ w, ushort* __restrict__ wt)
{
    const int i = blockIdx.x * 256 + threadIdx.x;   // < WT_ELEMS
    const int g = i / (9 * GC_ * GC_);
    const int rem = i % (9 * GC_ * GC_);
    const int tap = rem / (GC_ * GC_);
    const int rem2 = rem % (GC_ * GC_);
    const int oc = rem2 >> 6;
    const int ic = rem2 & 63;
    float v = w[(size_t)(tap * GC_ + ic) * NC_ + g * GC_ + oc];
    ushort hi = f2bf(v);
    ushort lo = f2bf(v - bf2f(hi));
    wt[i] = hi;
    wt[WT_ELEMS + i] = lo;
}

// =====================================================================
// Grouped 3x3 conv as split-bf16 implicit-GEMM MFMA.
// Block: (group g, 4 rows, batch b). 4 waves = 4 oc-16 tiles.
// A (input) staged hi/lo in XOR-swizzled LDS; B (weights) from L2 per tap.
// 3-product split (AhBh + AlBh + AhBl) => ~1e-5 rel error (fp32-like).
// =====================================================================
__global__ __launch_bounds__(256) void conv_mfma_k(
    const float* __restrict__ q, const ushort* __restrict__ wt,
    const float* __restrict__ bias, float* __restrict__ t)
{
    const int bid = blockIdx.x;
    const int g = bid % NG;
    const int rg = (bid / NG) & 7;      // row group: rows rg*4 .. rg*4+3
    const int b = bid / (NG * 8);
    const int y0 = rg * 4;

    // 6 halo rows x 34 halo cols x 64 ch, hi and lo planes
    __shared__ __align__(16) ushort At[2][6 * 34 * 64];

    const int tid = threadIdx.x;
    const int wv = tid >> 6;
    const int lane = tid & 63;
    const int c15 = lane & 15;
    const int lg = lane >> 4;
    const int oc = wv * 16 + c15;

    // ---- stage input tile (fp32 -> hi/lo bf16, swizzled) ----
    for (int idx = tid; idx < 6 * 34 * 8; idx += 256) {
        const int cell = idx >> 3;
        const int ch0 = (idx & 7) << 3;
        const int rr = cell / 34, cc = cell % 34;
        const int yy = y0 + rr - 1, xx = cc - 1;
        float v[8];
        if ((unsigned)yy < 32u && (unsigned)xx < 32u) {
            const float* src = &q[(size_t)((b * 32 + yy) * 32 + xx) * NC_ + g * GC_ + ch0];
            *(float4*)&v[0] = *(const float4*)src;
            *(float4*)&v[4] = *(const float4*)(src + 4);
        } else {
#pragma unroll
            for (int j = 0; j < 8; ++j) v[j] = 0.f;
        }
        bf16x8 hi8, lo8;
#pragma unroll
        for (int j = 0; j < 8; ++j) {
            ushort h = f2bf(v[j]);
            hi8[j] = (short)h;
            lo8[j] = (short)f2bf(v[j] - bf2f(h));
        }
        const int wi = cell * 64 + (ch0 ^ ((cc & 7) << 3));
        *(bf16x8*)&At[0][wi] = hi8;
        *(bf16x8*)&At[1][wi] = lo8;
    }

    const float bval = bias[g * GC_ + oc];
    f32x4 acc[8];
#pragma unroll
    for (int m = 0; m < 8; ++m) acc[m] = (f32x4){bval, bval, bval, bval};

    __syncthreads();

#pragma unroll
    for (int tap = 0; tap < 9; ++tap) {
        const int kh = tap / 3, kw = tap % 3;
        const ushort* wb = &wt[(size_t)((g * 9 + tap) * GC_ + oc) * GC_ + lg * 8];
        bf16x8 Bh0 = *(const bf16x8*)&wb[0];
        bf16x8 Bh1 = *(const bf16x8*)&wb[32];
        bf16x8 Bl0 = *(const bf16x8*)&wb[WT_ELEMS];
        bf16x8 Bl1 = *(const bf16x8*)&wb[WT_ELEMS + 32];
#pragma unroll
        for (int m = 0; m < 8; ++m) {
            const int rr = (m >> 1) + kh;
            const int cc = (m & 1) * 16 + kw + c15;
            const int base = (rr * 34 + cc) * 64;
            const int sw = (cc & 7) << 3;
            bf16x8 Ah0 = *(const bf16x8*)&At[0][base + ((lg * 8) ^ sw)];
            bf16x8 Ah1 = *(const bf16x8*)&At[0][base + ((32 + lg * 8) ^ sw)];
            bf16x8 Al0 = *(const bf16x8*)&At[1][base + ((lg * 8) ^ sw)];
            bf16x8 Al1 = *(const bf16x8*)&At[1][base + ((32 + lg * 8) ^ sw)];
            acc[m] = __builtin_amdgcn_mfma_f32_16x16x32_bf16(Ah0, Bh0, acc[m], 0, 0, 0);
            acc[m] = __builtin_amdgcn_mfma_f32_16x16x32_bf16(Ah1, Bh1, acc[m], 0, 0, 0);
            acc[m] = __builtin_amdgcn_mfma_f32_16x16x32_bf16(Al0, Bh0, acc[m], 0, 0, 0);
            acc[m] = __builtin_amdgcn_mfma_f32_16x16x32_bf16(Al1, Bh1, acc[m], 0, 0, 0);
            acc[m] = __builtin_amdgcn_mfma_f32_16x16x32_bf16(Ah0, Bl0, acc[m], 0, 0, 0);
            acc[m] = __builtin_amdgcn_mfma_f32_16x16x32_bf16(Ah1, Bl1, acc[m], 0, 0, 0);
        }
    }

    // ---- store: D row = position (lg*4+r), col = oc (c15) ----
#pragma unroll
    for (int m = 0; m < 8; ++m) {
        const int y = y0 + (m >> 1);
#pragma unroll
        for (int r = 0; r < 4; ++r) {
            const int x = (m & 1) * 16 + lg * 4 + r;
            t[(size_t)((b * 32 + y) * 32 + x) * NC_ + g * GC_ + oc] = acc[m][r];
        }
    }
}

// =====================================================================
// LayerNorm(384) + erf-GELU + per-group 64->2 proj + tanh*16 + ref grid.
// =====================================================================
__global__ __launch_bounds__(384) void ln_gelu_off_k(
    const float* __restrict__ t, const float* __restrict__ ln_g,
    const float* __restrict__ ln_b, const float* __restrict__ w_offp,
    float* __restrict__ warp)
{
    const int p = blockIdx.x;
    const int c = threadIdx.x;
    const int lane = c & 63;
    const int wv = c >> 6;

    __shared__ float red[8];
    float v = t[(size_t)p * NC_ + c];

    float s = v;
#pragma unroll
    for (int o = 32; o > 0; o >>= 1) s += __shfl_down(s, o, 64);
    if (lane == 0) red[wv] = s;
    __syncthreads();
    float mu = (red[0] + red[1] + red[2] + red[3] + red[4] + red[5]) * (1.f / 384.f);
    __syncthreads();

    float d = v - mu;
    s = d * d;
#pragma unroll
    for (int o = 32; o > 0; o >>= 1) s += __shfl_down(s, o, 64);
    if (lane == 0) red[wv] = s;
    __syncthreads();
    float var = (red[0] + red[1] + red[2] + red[3] + red[4] + red[5]) * (1.f / 384.f);

    float nv = (v - mu) * rsqrtf(var + 1e-3f) * ln_g[c] + ln_b[c];
    float gv = 0.5f * nv * (1.0f + erff(nv * 0.70710678118654752440f));

    float s0 = gv * w_offp[lane * 2 + 0];
    float s1 = gv * w_offp[lane * 2 + 1];
#pragma unroll
    for (int o = 32; o > 0; o >>= 1) {
        s0 += __shfl_down(s0, o, 64);
        s1 += __shfl_down(s1, o, 64);
    }
    if (lane == 0) {
        int b = p >> 10, ij = p & 1023;
        int i = ij >> 5, j = ij & 31;
        float off0 = tanhf(s0) * 16.0f;
        float off1 = tanhf(s1) * 16.0f;
        float px = off1 + (float)i;
        float py = off0 + (float)j;
        int bg = b * NG + wv;
        warp[((size_t)bg * NQ + ij) * 2 + 0] = px;
        warp[((size_t)bg * NQ + ij) * 2 + 1] = py;
    }
}

// =====================================================================
// Bilinear sampling with zero border.
// =====================================================================
__device__ inline float4 tap_load(const float* __restrict__ x, int b, int g,
                                  int yp, int xp, int ic4)
{
    int r = yp - 1, c = xp - 1;
    if ((unsigned)r < 32u && (unsigned)c < 32u)
        return *(const float4*)&x[(size_t)(((b * 32 + r) * 32 + c)) * NC_ + g * GC_ + ic4];
    return make_float4(0.f, 0.f, 0.f, 0.f);
}

__global__ __launch_bounds__(256) void sample_kk(
    const float* __restrict__ x, const float* __restrict__ warp,
    float* __restrict__ xs)
{
    const int gidx = blockIdx.x * 256 + threadIdx.x;
    const int ic4 = (gidx & 15) * 4;
    const int qq = (gidx >> 4) & 1023;
    const int bg = gidx >> 14;
    const int b = bg / NG, g = bg % NG;

    const float wx = warp[((size_t)bg * NQ + qq) * 2 + 0];
    const float wy = warp[((size_t)bg * NQ + qq) * 2 + 1];
    const float xq = wx + 1.0f, yq = wy + 1.0f;
    float x0 = fminf(fmaxf(floorf(xq), 0.f), 32.f);
    float y0 = fminf(fmaxf(floorf(yq), 0.f), 32.f);
    float ax = fminf(fmaxf(xq - x0, 0.f), 1.f);
    float ay = fminf(fmaxf(yq - y0, 0.f), 1.f);
    int xi = (int)x0, yi = (int)y0;

    float4 tl = tap_load(x, b, g, yi,     xi,     ic4);
    float4 tr = tap_load(x, b, g, yi,     xi + 1, ic4);
    float4 bl = tap_load(x, b, g, yi + 1, xi,     ic4);
    float4 br = tap_load(x, b, g, yi + 1, xi + 1, ic4);

    float4 top, bot, r;
    top.x = tl.x + ax * (tr.x - tl.x); top.y = tl.y + ax * (tr.y - tl.y);
    top.z = tl.z + ax * (tr.z - tl.z); top.w = tl.w + ax * (tr.w - tl.w);
    bot.x = bl.x + ax * (br.x - bl.x); bot.y = bl.y + ax * (br.y - bl.y);
    bot.z = bl.z + ax * (br.z - bl.z); bot.w = bl.w + ax * (br.w - bl.w);
    r.x = top.x + ay * (bot.x - top.x); r.y = top.y + ay * (bot.y - top.y);
    r.z = top.z + ay * (bot.z - top.z); r.w = top.w + ay * (bot.w - top.w);

    *(float4*)&xs[((size_t)b * NQ + qq) * NC_ + g * GC_ + ic4] = r;
}

// =====================================================================
// MFMA flash attention (bf16 inputs, fp32 accum). Unchanged from R2.
// =====================================================================
__global__ __launch_bounds__(256) void attn_mfma_k(
    const float* __restrict__ q, const ushort* __restrict__ kb,
    const ushort* __restrict__ vb, float* __restrict__ o)
{
    __shared__ __align__(16) ushort Vt[2048];       // [32c][64k], swizzled
    __shared__ __align__(16) ushort Pl[4][1024];    // per-wave [16q][64k], swizzled

    const int mt = blockIdx.x;
    const int bh = blockIdx.y;
    const int b = bh / NH, h = bh % NH;
    const int tid = threadIdx.x;
    const int w = tid >> 6;
    const int lane = tid & 63;
    const int c15 = lane & 15;
    const int lg = lane >> 4;

    const float scale = 0.17677669529663687f;

    bf16x8 qf;
    {
        const float* qp = &q[((size_t)b * NQ + mt * 64 + w * 16 + c15) * NC_ + h * HC_ + lg * 8];
        float tmp[8];
        *(float4*)&tmp[0] = *(const float4*)qp;
        *(float4*)&tmp[4] = *(const float4*)(qp + 4);
#pragma unroll
        for (int i = 0; i < 8; ++i) tmp[i] *= scale;
        qf = pack8(tmp);
    }

    f32x4 oacc[2];
    oacc[0] = (f32x4){0.f, 0.f, 0.f, 0.f};
    oacc[1] = (f32x4){0.f, 0.f, 0.f, 0.f};
    float m_i[4], l_i[4];
#pragma unroll
    for (int r = 0; r < 4; ++r) { m_i[r] = -INFINITY; l_i[r] = 0.f; }

    const int vc = tid >> 3;
    const int vk8 = (tid & 7) * 8;
    const int vt_widx = (vc * 64 + vk8) ^ ((vc & 7) << 3);

    for (int n0 = 0; n0 < NQ; n0 += 64) {
        __syncthreads();
        {
            const ushort* vp = &vb[((size_t)b * NQ + n0 + vk8) * NC_ + h * HC_ + vc];
            bf16x8 vv;
#pragma unroll
            for (int j = 0; j < 8; ++j) vv[j] = (short)vp[(size_t)j * NC_];
            *(bf16x8*)&Vt[vt_widx] = vv;
        }

        f32x4 sacc[4];
        {
            const ushort* kp = &kb[((size_t)b * NQ + n0 + c15) * NC_ + h * HC_ + lg * 8];
            const f32x4 z = (f32x4){0.f, 0.f, 0.f, 0.f};
#pragma unroll
            for (int kt = 0; kt < 4; ++kt) {
                bf16x8 kf = *(const bf16x8*)(kp + (size_t)kt * 16 * NC_);
                sacc[kt] = __builtin_amdgcn_mfma_f32_16x16x32_bf16(qf, kf, z, 0, 0, 0);
            }
        }
        __syncthreads();

        float pv[4][4];
#pragma unroll
        for (int r = 0; r < 4; ++r) {
            float mx = fmaxf(fmaxf(sacc[0][r], sacc[1][r]), fmaxf(sacc[2][r], sacc[3][r]));
            mx = fmaxf(mx, __shfl_xor(mx, 1, 16));
            mx = fmaxf(mx, __shfl_xor(mx, 2, 16));
            mx = fmaxf(mx, __shfl_xor(mx, 4, 16));
            mx = fmaxf(mx, __shfl_xor(mx, 8, 16));
            float mn = fmaxf(m_i[r], mx);
            float al = __expf(m_i[r] - mn);
            m_i[r] = mn;
            float p0 = __expf(sacc[0][r] - mn);
            float p1 = __expf(sacc[1][r] - mn);
            float p2 = __expf(sacc[2][r] - mn);
            float p3 = __expf(sacc[3][r] - mn);
            pv[0][r] = p0; pv[1][r] = p1; pv[2][r] = p2; pv[3][r] = p3;
            float rs = p0 + p1 + p2 + p3;
            rs += __shfl_xor(rs, 1, 16);
            rs += __shfl_xor(rs, 2, 16);
            rs += __shfl_xor(rs, 4, 16);
            rs += __shfl_xor(rs, 8, 16);
            l_i[r] = l_i[r] * al + rs;
            oacc[0][r] *= al;
            oacc[1][r] *= al;
        }

#pragma unroll
        for (int r = 0; r < 4; ++r) {
            const int qq = lg * 4 + r;
            const int sw = (qq & 7) << 3;
#pragma unroll
            for (int kt = 0; kt < 4; ++kt)
                Pl[w][qq * 64 + ((kt * 16 + c15) ^ sw)] = f2bf(pv[kt][r]);
        }

#pragma unroll
        for (int kblk = 0; kblk < 2; ++kblk) {
            bf16x8 pf = *(bf16x8*)&Pl[w][c15 * 64 + ((kblk * 32 + lg * 8) ^ ((c15 & 7) << 3))];
#pragma unroll
            for (int ct = 0; ct < 2; ++ct) {
                const int cc = ct * 16 + c15;
                bf16x8 vf = *(bf16x8*)&Vt[(cc * 64 + kblk * 32 + lg * 8) ^ ((cc & 7) << 3)];
                oacc[ct] = __builtin_amdgcn_mfma_f32_16x16x32_bf16(pf, vf, oacc[ct], 0, 0, 0);
            }
        }
    }

#pragma unroll
    for (int r = 0; r < 4; ++r) {
        float inv = 1.f / l_i[r];
        size_t row = (size_t)b * NQ + mt * 64 + w * 16 + lg * 4 + r;
        o[row * NC_ + h * HC_ + c15]      = oacc[0][r] * inv;
        o[row * NC_ + h * HC_ + 16 + c15] = oacc[1][r] * inv;
    }
}

// =====================================================================
// Launch. ws floats: q | t(=attn-out) | xs | kb(bf16) | vb(bf16)+wt | warp
// =====================================================================
extern "C" void kernel_launch(void* const* d_in, const int* in_sizes, int n_in,
                              void* d_out, int out_size, void* d_ws, size_t ws_size,
                              hipStream_t stream)
{
    const float* x      = (const float*)d_in[0];
    const float* w_q    = (const float*)d_in[1];
    const float* b_q    = (const float*)d_in[2];
    const float* w_off0 = (const float*)d_in[3];
    const float* b_off0 = (const float*)d_in[4];
    const float* ln_g   = (const float*)d_in[5];
    const float* ln_b   = (const float*)d_in[6];
    const float* w_offp = (const float*)d_in[7];
    const float* w_k    = (const float*)d_in[8];
    const float* b_k    = (const float*)d_in[9];
    const float* w_v    = (const float*)d_in[10];
    const float* b_v    = (const float*)d_in[11];
    const float* w_o    = (const float*)d_in[12];
    const float* b_o    = (const float*)d_in[13];

    float* ws = (float*)d_ws;
    float*  q    = ws;
    float*  t    = ws + (size_t)NPOS_ELEMS;       // reused as attention output
    float*  xs   = ws + (size_t)2 * NPOS_ELEMS;
    ushort* kb16 = (ushort*)(ws + (size_t)3 * NPOS_ELEMS);
    ushort* vb16 = (ushort*)(ws + (size_t)4 * NPOS_ELEMS);
    // conv weights (hi/lo bf16) carved from unused upper half of the vb slot
    ushort* wt   = (ushort*)(ws + (size_t)4 * NPOS_ELEMS + NPOS_ELEMS / 2);
    float*  wp   = ws + (size_t)5 * NPOS_ELEMS;   // warp coords

    const int M = BB * NQ;   // 8192

    wconv_t_k<<<WT_ELEMS / 256, 256, 0, stream>>>(w_off0, wt);
    gemm_bias_k<0><<<dim3(M / 64, NC_ / 64), 256, 0, stream>>>(x, w_q, b_q, (void*)q, M, NC_, NC_);
    conv_mfma_k<<<BB * 8 * NG, 256, 0, stream>>>(q, wt, b_off0, t);
    ln_gelu_off_k<<<M, 384, 0, stream>>>(t, ln_g, ln_b, w_offp, wp);
    sample_kk<<<(BB * NG * NQ * 16) / 256, 256, 0, stream>>>(x, wp, xs);
    gemm_bias_k<1><<<dim3(M / 64, NC_ / 64), 256, 0, stream>>>(xs, w_k, b_k, (void*)kb16, M, NC_, NC_);
    gemm_bias_k<1><<<dim3(M / 64, NC_ / 64), 256, 0, stream>>>(xs, w_v, b_v, (void*)vb16, M, NC_, NC_);
    attn_mfma_k<<<dim3(NQ / 64, BB * NH), 256, 0, stream>>>(q, kb16, vb16, t);
    gemm_bias_k<0><<<dim3(M / 64, NC_ / 64), 256, 0, stream>>>(t, w_o, b_o, (void*)d_out, M, NC_, NC_);
}

// Round 4
// 387.515 us; speedup vs baseline: 1.6624x; 1.0079x over previous
//
#include <hip/hip_runtime.h>
#include <math.h>

// Problem sizes (fixed)
#define BB 8
#define NC_ 384
#define NG 6
#define GC_ 64
#define NH 12
#define HC_ 32
#define NQ 1024
#define NPOS_ELEMS (BB*NQ*NC_)       // 3,145,728
#define WT_ELEMS (NG*9*GC_*GC_)      // 221,184 per conv split plane
#define WSQ (NC_*NC_)                // 147,456 per square-weight plane

typedef short bf16x8 __attribute__((ext_vector_type(8)));
typedef float f32x4  __attribute__((ext_vector_type(4)));

__device__ inline ushort f2bf(float f) {
    union { float f; unsigned u; } v; v.f = f;
    unsigned r = v.u + 0x7FFFu + ((v.u >> 16) & 1u);   // RNE
    return (ushort)(r >> 16);
}
__device__ inline float bf2f(ushort h) {
    union { unsigned u; float f; } v; v.u = ((unsigned)h) << 16;
    return v.f;
}
__device__ inline bf16x8 pack8(const float* f) {
    bf16x8 r;
#pragma unroll
    for (int i = 0; i < 8; ++i) r[i] = (short)f2bf(f[i]);
    return r;
}

// =====================================================================
// Square weight transpose + split: W[k][n] fp32 -> wt[mat][plane][n][k] bf16.
// Grid (6,6,4); 64x64 tiles through LDS.
// =====================================================================
__global__ __launch_bounds__(256) void wsplit_k(
    const float* __restrict__ w0, const float* __restrict__ w1,
    const float* __restrict__ w2, const float* __restrict__ w3,
    ushort* __restrict__ wt)
{
    const int mat = blockIdx.z;
    const float* W = mat == 0 ? w0 : mat == 1 ? w1 : mat == 2 ? w2 : w3;
    const int kt0 = blockIdx.x * 64, nt0 = blockIdx.y * 64;
    __shared__ float Ts[64][68];
    const int tid = threadIdx.x;
    {
        const int kl = tid >> 4, nl = (tid & 15) * 4;
#pragma unroll
        for (int rr = 0; rr < 4; ++rr)
            *(float4*)&Ts[kl + rr * 16][nl] =
                *(const float4*)&W[(size_t)(kt0 + kl + rr * 16) * NC_ + nt0 + nl];
    }
    __syncthreads();
    {
        const int n = tid >> 2, k0 = (tid & 3) * 16;
        ushort* dst = &wt[(size_t)mat * 2 * WSQ + (size_t)(nt0 + n) * NC_ + kt0 + k0];
#pragma unroll
        for (int j8 = 0; j8 < 16; j8 += 8) {
            bf16x8 hi8, lo8;
#pragma unroll
            for (int j = 0; j < 8; ++j) {
                float f = Ts[k0 + j8 + j][n];
                ushort h = f2bf(f);
                hi8[j] = (short)h;
                lo8[j] = (short)f2bf(f - bf2f(h));
            }
            *(bf16x8*)&dst[j8] = hi8;
            *(bf16x8*)&dst[WSQ + j8] = lo8;
        }
    }
}

// =====================================================================
// Split-bf16 MFMA GEMM: C[M,384] = A[M,384] @ W + bias. Wt = [plane][n][k].
// 64x64 tile, BK=64, 4 waves x (16 rows x 64 cols). 3-product split.
// =====================================================================
template<int OUT_BF16>
__global__ __launch_bounds__(256) void gemm_mfma_k(
    const float* __restrict__ A, const ushort* __restrict__ Wt,
    const float* __restrict__ bias, void* __restrict__ Cv, int M)
{
    __shared__ __align__(16) ushort At[2][64 * 64];
    const int m0 = blockIdx.x * 64;
    const int n0 = blockIdx.y * 64;
    const int tid = threadIdx.x;
    const int w = tid >> 6;
    const int lane = tid & 63;
    const int c15 = lane & 15;
    const int lg = lane >> 4;

    f32x4 acc[4];
#pragma unroll
    for (int ct = 0; ct < 4; ++ct) acc[ct] = (f32x4){0.f, 0.f, 0.f, 0.f};

    const int sm = tid >> 2;           // staging row 0..63
    const int sk0 = (tid & 3) * 16;    // staging k 0,16,32,48

    for (int ks = 0; ks < NC_; ks += 64) {
        // ---- stage A tile hi/lo (swizzled) ----
        {
            const float* src = &A[(size_t)(m0 + sm) * NC_ + ks + sk0];
            float v[16];
            *(float4*)&v[0]  = *(const float4*)&src[0];
            *(float4*)&v[4]  = *(const float4*)&src[4];
            *(float4*)&v[8]  = *(const float4*)&src[8];
            *(float4*)&v[12] = *(const float4*)&src[12];
#pragma unroll
            for (int j8 = 0; j8 < 16; j8 += 8) {
                bf16x8 hi8, lo8;
#pragma unroll
                for (int j = 0; j < 8; ++j) {
                    float f = v[j8 + j];
                    ushort h = f2bf(f);
                    hi8[j] = (short)h;
                    lo8[j] = (short)f2bf(f - bf2f(h));
                }
                const int idx = sm * 64 + ((sk0 + j8) ^ ((sm & 7) << 3));
                *(bf16x8*)&At[0][idx] = hi8;
                *(bf16x8*)&At[1][idx] = lo8;
            }
        }
        __syncthreads();
#pragma unroll
        for (int kc = 0; kc < 64; kc += 32) {
            const int arow = w * 16 + c15;
            const int aidx = arow * 64 + ((kc + lg * 8) ^ ((arow & 7) << 3));
            bf16x8 Ah = *(bf16x8*)&At[0][aidx];
            bf16x8 Al = *(bf16x8*)&At[1][aidx];
            const ushort* wb = &Wt[(size_t)(n0 + c15) * NC_ + ks + kc + lg * 8];
#pragma unroll
            for (int ct = 0; ct < 4; ++ct) {
                bf16x8 Bh = *(const bf16x8*)&wb[(size_t)ct * 16 * NC_];
                bf16x8 Bl = *(const bf16x8*)&wb[WSQ + (size_t)ct * 16 * NC_];
                acc[ct] = __builtin_amdgcn_mfma_f32_16x16x32_bf16(Ah, Bh, acc[ct], 0, 0, 0);
                acc[ct] = __builtin_amdgcn_mfma_f32_16x16x32_bf16(Al, Bh, acc[ct], 0, 0, 0);
                acc[ct] = __builtin_amdgcn_mfma_f32_16x16x32_bf16(Ah, Bl, acc[ct], 0, 0, 0);
            }
        }
        __syncthreads();
    }

#pragma unroll
    for (int ct = 0; ct < 4; ++ct) {
        const int col = n0 + ct * 16 + c15;
        const float bv = bias[col];
#pragma unroll
        for (int r = 0; r < 4; ++r) {
            const size_t row = m0 + w * 16 + lg * 4 + r;
            const float val = acc[ct][r] + bv;
            if constexpr (OUT_BF16)
                ((ushort*)Cv)[row * NC_ + col] = f2bf(val);
            else
                ((float*)Cv)[row * NC_ + col] = val;
        }
    }
}

// =====================================================================
// Conv weight transpose + split (unchanged, validated).
// =====================================================================
__global__ __launch_bounds__(256) void wconv_t_k(
    const float* __restrict__ w, ushort* __restrict__ wt)
{
    const int i = blockIdx.x * 256 + threadIdx.x;
    const int g = i / (9 * GC_ * GC_);
    const int rem = i % (9 * GC_ * GC_);
    const int tap = rem / (GC_ * GC_);
    const int rem2 = rem % (GC_ * GC_);
    const int oc = rem2 >> 6;
    const int ic = rem2 & 63;
    float v = w[(size_t)(tap * GC_ + ic) * NC_ + g * GC_ + oc];
    ushort hi = f2bf(v);
    ushort lo = f2bf(v - bf2f(hi));
    wt[i] = hi;
    wt[WT_ELEMS + i] = lo;
}

// =====================================================================
// Grouped 3x3 conv as split-bf16 implicit-GEMM MFMA (unchanged, validated).
// =====================================================================
__global__ __launch_bounds__(256) void conv_mfma_k(
    const float* __restrict__ q, const ushort* __restrict__ wt,
    const float* __restrict__ bias, float* __restrict__ t)
{
    const int bid = blockIdx.x;
    const int g = bid % NG;
    const int rg = (bid / NG) & 7;
    const int b = bid / (NG * 8);
    const int y0 = rg * 4;

    __shared__ __align__(16) ushort At[2][6 * 34 * 64];

    const int tid = threadIdx.x;
    const int wv = tid >> 6;
    const int lane = tid & 63;
    const int c15 = lane & 15;
    const int lg = lane >> 4;
    const int oc = wv * 16 + c15;

    for (int idx = tid; idx < 6 * 34 * 8; idx += 256) {
        const int cell = idx >> 3;
        const int ch0 = (idx & 7) << 3;
        const int rr = cell / 34, cc = cell % 34;
        const int yy = y0 + rr - 1, xx = cc - 1;
        float v[8];
        if ((unsigned)yy < 32u && (unsigned)xx < 32u) {
            const float* src = &q[(size_t)((b * 32 + yy) * 32 + xx) * NC_ + g * GC_ + ch0];
            *(float4*)&v[0] = *(const float4*)src;
            *(float4*)&v[4] = *(const float4*)(src + 4);
        } else {
#pragma unroll
            for (int j = 0; j < 8; ++j) v[j] = 0.f;
        }
        bf16x8 hi8, lo8;
#pragma unroll
        for (int j = 0; j < 8; ++j) {
            ushort h = f2bf(v[j]);
            hi8[j] = (short)h;
            lo8[j] = (short)f2bf(v[j] - bf2f(h));
        }
        const int wi = cell * 64 + (ch0 ^ ((cc & 7) << 3));
        *(bf16x8*)&At[0][wi] = hi8;
        *(bf16x8*)&At[1][wi] = lo8;
    }

    const float bval = bias[g * GC_ + oc];
    f32x4 acc[8];
#pragma unroll
    for (int m = 0; m < 8; ++m) acc[m] = (f32x4){bval, bval, bval, bval};

    __syncthreads();

#pragma unroll
    for (int tap = 0; tap < 9; ++tap) {
        const int kh = tap / 3, kw = tap % 3;
        const ushort* wb = &wt[(size_t)((g * 9 + tap) * GC_ + oc) * GC_ + lg * 8];
        bf16x8 Bh0 = *(const bf16x8*)&wb[0];
        bf16x8 Bh1 = *(const bf16x8*)&wb[32];
        bf16x8 Bl0 = *(const bf16x8*)&wb[WT_ELEMS];
        bf16x8 Bl1 = *(const bf16x8*)&wb[WT_ELEMS + 32];
#pragma unroll
        for (int m = 0; m < 8; ++m) {
            const int rr = (m >> 1) + kh;
            const int cc = (m & 1) * 16 + kw + c15;
            const int base = (rr * 34 + cc) * 64;
            const int sw = (cc & 7) << 3;
            bf16x8 Ah0 = *(const bf16x8*)&At[0][base + ((lg * 8) ^ sw)];
            bf16x8 Ah1 = *(const bf16x8*)&At[0][base + ((32 + lg * 8) ^ sw)];
            bf16x8 Al0 = *(const bf16x8*)&At[1][base + ((lg * 8) ^ sw)];
            bf16x8 Al1 = *(const bf16x8*)&At[1][base + ((32 + lg * 8) ^ sw)];
            acc[m] = __builtin_amdgcn_mfma_f32_16x16x32_bf16(Ah0, Bh0, acc[m], 0, 0, 0);
            acc[m] = __builtin_amdgcn_mfma_f32_16x16x32_bf16(Ah1, Bh1, acc[m], 0, 0, 0);
            acc[m] = __builtin_amdgcn_mfma_f32_16x16x32_bf16(Al0, Bh0, acc[m], 0, 0, 0);
            acc[m] = __builtin_amdgcn_mfma_f32_16x16x32_bf16(Al1, Bh1, acc[m], 0, 0, 0);
            acc[m] = __builtin_amdgcn_mfma_f32_16x16x32_bf16(Ah0, Bl0, acc[m], 0, 0, 0);
            acc[m] = __builtin_amdgcn_mfma_f32_16x16x32_bf16(Ah1, Bl1, acc[m], 0, 0, 0);
        }
    }

#pragma unroll
    for (int m = 0; m < 8; ++m) {
        const int y = y0 + (m >> 1);
#pragma unroll
        for (int r = 0; r < 4; ++r) {
            const int x = (m & 1) * 16 + lg * 4 + r;
            t[(size_t)((b * 32 + y) * 32 + x) * NC_ + g * GC_ + oc] = acc[m][r];
        }
    }
}

// =====================================================================
// LayerNorm(384) + erf-GELU + per-group 64->2 proj + tanh*16 + ref grid.
// =====================================================================
__global__ __launch_bounds__(384) void ln_gelu_off_k(
    const float* __restrict__ t, const float* __restrict__ ln_g,
    const float* __restrict__ ln_b, const float* __restrict__ w_offp,
    float* __restrict__ warp)
{
    const int p = blockIdx.x;
    const int c = threadIdx.x;
    const int lane = c & 63;
    const int wv = c >> 6;

    __shared__ float red[8];
    float v = t[(size_t)p * NC_ + c];

    float s = v;
#pragma unroll
    for (int o = 32; o > 0; o >>= 1) s += __shfl_down(s, o, 64);
    if (lane == 0) red[wv] = s;
    __syncthreads();
    float mu = (red[0] + red[1] + red[2] + red[3] + red[4] + red[5]) * (1.f / 384.f);
    __syncthreads();

    float d = v - mu;
    s = d * d;
#pragma unroll
    for (int o = 32; o > 0; o >>= 1) s += __shfl_down(s, o, 64);
    if (lane == 0) red[wv] = s;
    __syncthreads();
    float var = (red[0] + red[1] + red[2] + red[3] + red[4] + red[5]) * (1.f / 384.f);

    float nv = (v - mu) * rsqrtf(var + 1e-3f) * ln_g[c] + ln_b[c];
    float gv = 0.5f * nv * (1.0f + erff(nv * 0.70710678118654752440f));

    float s0 = gv * w_offp[lane * 2 + 0];
    float s1 = gv * w_offp[lane * 2 + 1];
#pragma unroll
    for (int o = 32; o > 0; o >>= 1) {
        s0 += __shfl_down(s0, o, 64);
        s1 += __shfl_down(s1, o, 64);
    }
    if (lane == 0) {
        int b = p >> 10, ij = p & 1023;
        int i = ij >> 5, j = ij & 31;
        float off0 = tanhf(s0) * 16.0f;
        float off1 = tanhf(s1) * 16.0f;
        float px = off1 + (float)i;
        float py = off0 + (float)j;
        int bg = b * NG + wv;
        warp[((size_t)bg * NQ + ij) * 2 + 0] = px;
        warp[((size_t)bg * NQ + ij) * 2 + 1] = py;
    }
}

// =====================================================================
// Bilinear sampling with zero border (unchanged).
// =====================================================================
__device__ inline float4 tap_load(const float* __restrict__ x, int b, int g,
                                  int yp, int xp, int ic4)
{
    int r = yp - 1, c = xp - 1;
    if ((unsigned)r < 32u && (unsigned)c < 32u)
        return *(const float4*)&x[(size_t)(((b * 32 + r) * 32 + c)) * NC_ + g * GC_ + ic4];
    return make_float4(0.f, 0.f, 0.f, 0.f);
}

__global__ __launch_bounds__(256) void sample_kk(
    const float* __restrict__ x, const float* __restrict__ warp,
    float* __restrict__ xs)
{
    const int gidx = blockIdx.x * 256 + threadIdx.x;
    const int ic4 = (gidx & 15) * 4;
    const int qq = (gidx >> 4) & 1023;
    const int bg = gidx >> 14;
    const int b = bg / NG, g = bg % NG;

    const float wx = warp[((size_t)bg * NQ + qq) * 2 + 0];
    const float wy = warp[((size_t)bg * NQ + qq) * 2 + 1];
    const float xq = wx + 1.0f, yq = wy + 1.0f;
    float x0 = fminf(fmaxf(floorf(xq), 0.f), 32.f);
    float y0 = fminf(fmaxf(floorf(yq), 0.f), 32.f);
    float ax = fminf(fmaxf(xq - x0, 0.f), 1.f);
    float ay = fminf(fmaxf(yq - y0, 0.f), 1.f);
    int xi = (int)x0, yi = (int)y0;

    float4 tl = tap_load(x, b, g, yi,     xi,     ic4);
    float4 tr = tap_load(x, b, g, yi,     xi + 1, ic4);
    float4 bl = tap_load(x, b, g, yi + 1, xi,     ic4);
    float4 br = tap_load(x, b, g, yi + 1, xi + 1, ic4);

    float4 top, bot, r;
    top.x = tl.x + ax * (tr.x - tl.x); top.y = tl.y + ax * (tr.y - tl.y);
    top.z = tl.z + ax * (tr.z - tl.z); top.w = tl.w + ax * (tr.w - tl.w);
    bot.x = bl.x + ax * (br.x - bl.x); bot.y = bl.y + ax * (br.y - bl.y);
    bot.z = bl.z + ax * (br.z - bl.z); bot.w = bl.w + ax * (br.w - bl.w);
    r.x = top.x + ay * (bot.x - top.x); r.y = top.y + ay * (bot.y - top.y);
    r.z = top.z + ay * (bot.z - top.z); r.w = top.w + ay * (bot.w - top.w);

    *(float4*)&xs[((size_t)b * NQ + qq) * NC_ + g * GC_ + ic4] = r;
}

// =====================================================================
// V transpose: vb[b][n][384] bf16 (head slice) -> vt[b][h][c][n] bf16.
// Grid = B*H*16, 64n x 32c tiles through LDS.
// =====================================================================
__global__ __launch_bounds__(256) void vtrans_k(
    const ushort* __restrict__ vb, ushort* __restrict__ vt)
{
    const int bid = blockIdx.x;
    const int nt = bid & 15;
    const int h = (bid >> 4) % NH;
    const int b = bid / (16 * NH);
    const int n0 = nt * 64;
    __shared__ __align__(16) ushort Ls[32][72];
    const int tid = threadIdx.x;
    {
        const int n = tid >> 2, c0 = (tid & 3) * 8;
        bf16x8 v = *(const bf16x8*)&vb[(size_t)(b * NQ + n0 + n) * NC_ + h * HC_ + c0];
#pragma unroll
        for (int j = 0; j < 8; ++j) Ls[c0 + j][n] = (ushort)v[j];
    }
    __syncthreads();
    {
        const int c = tid >> 3, n1 = (tid & 7) * 8;
        bf16x8 o = *(const bf16x8*)&Ls[c][n1];
        *(bf16x8*)&vt[(size_t)((b * NH + h) * HC_ + c) * NQ + n0 + n1] = o;
    }
}

// =====================================================================
// Barrier-free MFMA flash attention. 4 independent waves per block,
// 16 queries each. K from global bf16; V from pre-transposed vt (global);
// P bounced through per-wave LDS (no cross-wave coupling -> no barriers).
// =====================================================================
__global__ __launch_bounds__(256) void attn_mfma_k(
    const float* __restrict__ q, const ushort* __restrict__ kb,
    const ushort* __restrict__ vt, float* __restrict__ o)
{
    __shared__ __align__(16) ushort Pl[4][1024];

    const int mt = blockIdx.x;
    const int bh = blockIdx.y;
    const int b = bh / NH, h = bh % NH;
    const int tid = threadIdx.x;
    const int w = tid >> 6;
    const int lane = tid & 63;
    const int c15 = lane & 15;
    const int lg = lane >> 4;

    const float scale = 0.17677669529663687f;

    bf16x8 qf;
    {
        const float* qp = &q[((size_t)b * NQ + mt * 64 + w * 16 + c15) * NC_ + h * HC_ + lg * 8];
        float tmp[8];
        *(float4*)&tmp[0] = *(const float4*)qp;
        *(float4*)&tmp[4] = *(const float4*)(qp + 4);
#pragma unroll
        for (int i = 0; i < 8; ++i) tmp[i] *= scale;
        qf = pack8(tmp);
    }

    f32x4 oacc[2];
    oacc[0] = (f32x4){0.f, 0.f, 0.f, 0.f};
    oacc[1] = (f32x4){0.f, 0.f, 0.f, 0.f};
    float m_i[4], l_i[4];
#pragma unroll
    for (int r = 0; r < 4; ++r) { m_i[r] = -INFINITY; l_i[r] = 0.f; }

    const size_t bh32 = (size_t)(b * NH + h) * HC_;   // vt row base (x1024)

    for (int n0 = 0; n0 < NQ; n0 += 64) {
        // ---- K frags from global + S = Q.K^T ----
        f32x4 sacc[4];
        {
            const ushort* kp = &kb[((size_t)b * NQ + n0 + c15) * NC_ + h * HC_ + lg * 8];
            const f32x4 z = (f32x4){0.f, 0.f, 0.f, 0.f};
#pragma unroll
            for (int kt = 0; kt < 4; ++kt) {
                bf16x8 kf = *(const bf16x8*)(kp + (size_t)kt * 16 * NC_);
                sacc[kt] = __builtin_amdgcn_mfma_f32_16x16x32_bf16(qf, kf, z, 0, 0, 0);
            }
        }

        // ---- online softmax ----
        float pv[4][4];
#pragma unroll
        for (int r = 0; r < 4; ++r) {
            float mx = fmaxf(fmaxf(sacc[0][r], sacc[1][r]), fmaxf(sacc[2][r], sacc[3][r]));
            mx = fmaxf(mx, __shfl_xor(mx, 1, 16));
            mx = fmaxf(mx, __shfl_xor(mx, 2, 16));
            mx = fmaxf(mx, __shfl_xor(mx, 4, 16));
            mx = fmaxf(mx, __shfl_xor(mx, 8, 16));
            float mn = fmaxf(m_i[r], mx);
            float al = __expf(m_i[r] - mn);
            m_i[r] = mn;
            float p0 = __expf(sacc[0][r] - mn);
            float p1 = __expf(sacc[1][r] - mn);
            float p2 = __expf(sacc[2][r] - mn);
            float p3 = __expf(sacc[3][r] - mn);
            pv[0][r] = p0; pv[1][r] = p1; pv[2][r] = p2; pv[3][r] = p3;
            float rs = p0 + p1 + p2 + p3;
            rs += __shfl_xor(rs, 1, 16);
            rs += __shfl_xor(rs, 2, 16);
            rs += __shfl_xor(rs, 4, 16);
            rs += __shfl_xor(rs, 8, 16);
            l_i[r] = l_i[r] * al + rs;
            oacc[0][r] *= al;
            oacc[1][r] *= al;
        }

        // ---- P -> per-wave LDS (bf16, swizzled); same-wave RAW, no barrier ----
#pragma unroll
        for (int r = 0; r < 4; ++r) {
            const int qq = lg * 4 + r;
            const int sw = (qq & 7) << 3;
#pragma unroll
            for (int kt = 0; kt < 4; ++kt)
                Pl[w][qq * 64 + ((kt * 16 + c15) ^ sw)] = f2bf(pv[kt][r]);
        }

        // ---- O += P.V  (V^T frags straight from global vt) ----
#pragma unroll
        for (int kblk = 0; kblk < 2; ++kblk) {
            bf16x8 pf = *(bf16x8*)&Pl[w][c15 * 64 + ((kblk * 32 + lg * 8) ^ ((c15 & 7) << 3))];
#pragma unroll
            for (int ct = 0; ct < 2; ++ct) {
                const int cc = ct * 16 + c15;
                bf16x8 vf = *(const bf16x8*)&vt[((bh32 + cc) << 10) + n0 + kblk * 32 + lg * 8];
                oacc[ct] = __builtin_amdgcn_mfma_f32_16x16x32_bf16(pf, vf, oacc[ct], 0, 0, 0);
            }
        }
    }

#pragma unroll
    for (int r = 0; r < 4; ++r) {
        float inv = 1.f / l_i[r];
        size_t row = (size_t)b * NQ + mt * 64 + w * 16 + lg * 4 + r;
        o[row * NC_ + h * HC_ + c15]      = oacc[0][r] * inv;
        o[row * NC_ + h * HC_ + 16 + c15] = oacc[1][r] * inv;
    }
}

// =====================================================================
// Launch. ws floats:
// q | t(=attn out) | xs | [kb16|vb16] | [vt|wtconv|wtsq] | wp
// =====================================================================
extern "C" void kernel_launch(void* const* d_in, const int* in_sizes, int n_in,
                              void* d_out, int out_size, void* d_ws, size_t ws_size,
                              hipStream_t stream)
{
    const float* x      = (const float*)d_in[0];
    const float* w_q    = (const float*)d_in[1];
    const float* b_q    = (const float*)d_in[2];
    const float* w_off0 = (const float*)d_in[3];
    const float* b_off0 = (const float*)d_in[4];
    const float* ln_g   = (const float*)d_in[5];
    const float* ln_b   = (const float*)d_in[6];
    const float* w_offp = (const float*)d_in[7];
    const float* w_k    = (const float*)d_in[8];
    const float* b_k    = (const float*)d_in[9];
    const float* w_v    = (const float*)d_in[10];
    const float* b_v    = (const float*)d_in[11];
    const float* w_o    = (const float*)d_in[12];
    const float* b_o    = (const float*)d_in[13];

    float* ws = (float*)d_ws;
    float*  q    = ws;
    float*  t    = ws + (size_t)NPOS_ELEMS;
    float*  xs   = ws + (size_t)2 * NPOS_ELEMS;
    ushort* kb16 = (ushort*)(ws + (size_t)3 * NPOS_ELEMS);
    ushort* vb16 = kb16 + NPOS_ELEMS;
    ushort* vt   = (ushort*)(ws + (size_t)4 * NPOS_ELEMS);
    ushort* wtc  = vt + NPOS_ELEMS;                 // conv weights hi/lo
    ushort* wtsq = wtc + 2 * WT_ELEMS;              // 4 square mats hi/lo
    float*  wp   = ws + (size_t)5 * NPOS_ELEMS;

    ushort* wtq = wtsq;
    ushort* wtk = wtsq + 2 * WSQ;
    ushort* wtv = wtsq + 4 * WSQ;
    ushort* wto = wtsq + 6 * WSQ;

    const int M = BB * NQ;   // 8192

    wconv_t_k<<<WT_ELEMS / 256, 256, 0, stream>>>(w_off0, wtc);
    wsplit_k<<<dim3(6, 6, 4), 256, 0, stream>>>(w_q, w_k, w_v, w_o, wtsq);
    gemm_mfma_k<0><<<dim3(M / 64, 6), 256, 0, stream>>>(x, wtq, b_q, (void*)q, M);
    conv_mfma_k<<<BB * 8 * NG, 256, 0, stream>>>(q, wtc, b_off0, t);
    ln_gelu_off_k<<<M, 384, 0, stream>>>(t, ln_g, ln_b, w_offp, wp);
    sample_kk<<<(BB * NG * NQ * 16) / 256, 256, 0, stream>>>(x, wp, xs);
    gemm_mfma_k<1><<<dim3(M / 64, 6), 256, 0, stream>>>(xs, wtk, b_k, (void*)kb16, M);
    gemm_mfma_k<1><<<dim3(M / 64, 6), 256, 0, stream>>>(xs, wtv, b_v, (void*)vb16, M);
    vtrans_k<<<BB * NH * 16, 256, 0, stream>>>(vb16, vt);
    attn_mfma_k<<<dim3(NQ / 64, BB * NH), 256, 0, stream>>>(q, kb16, vt, t);
    gemm_mfma_k<0><<<dim3(M / 64, 6), 256, 0, stream>>>(t, wto, b_o, (void*)d_out, M);
}

// Round 5
// 384.146 us; speedup vs baseline: 1.6769x; 1.0088x over previous
//
#include <hip/hip_runtime.h>
#include <math.h>

// Problem sizes (fixed)
#define BB 8
#define NC_ 384
#define NG 6
#define GC_ 64
#define NH 12
#define HC_ 32
#define NQ 1024
#define NPOS_ELEMS (BB*NQ*NC_)       // 3,145,728
#define WT_ELEMS (NG*9*GC_*GC_)      // 221,184 per conv split plane
#define WSQ (NC_*NC_)                // 147,456 per square-weight plane

typedef short bf16x8 __attribute__((ext_vector_type(8)));
typedef float f32x4  __attribute__((ext_vector_type(4)));

__device__ inline ushort f2bf(float f) {
    union { float f; unsigned u; } v; v.f = f;
    unsigned r = v.u + 0x7FFFu + ((v.u >> 16) & 1u);   // RNE
    return (ushort)(r >> 16);
}
__device__ inline float bf2f(ushort h) {
    union { unsigned u; float f; } v; v.u = ((unsigned)h) << 16;
    return v.f;
}
__device__ inline bf16x8 pack8(const float* f) {
    bf16x8 r;
#pragma unroll
    for (int i = 0; i < 8; ++i) r[i] = (short)f2bf(f[i]);
    return r;
}

// =====================================================================
// fp32 -> hi/lo bf16 split (hi at [0,n), lo at [n,2n)).
// =====================================================================
__global__ __launch_bounds__(256) void split_k(
    const float* __restrict__ in, ushort* __restrict__ out, int n)
{
    const int i = (blockIdx.x * 256 + threadIdx.x) * 4;
    float4 v = *(const float4*)&in[i];
    ushort4 hi, lo;
    hi.x = f2bf(v.x); lo.x = f2bf(v.x - bf2f(hi.x));
    hi.y = f2bf(v.y); lo.y = f2bf(v.y - bf2f(hi.y));
    hi.z = f2bf(v.z); lo.z = f2bf(v.z - bf2f(hi.z));
    hi.w = f2bf(v.w); lo.w = f2bf(v.w - bf2f(hi.w));
    *(ushort4*)&out[i] = hi;
    *(ushort4*)&out[n + i] = lo;
}

// =====================================================================
// Square weight transpose + split: W[k][n] fp32 -> wt[mat][plane][n][k] bf16.
// =====================================================================
__global__ __launch_bounds__(256) void wsplit_k(
    const float* __restrict__ w0, const float* __restrict__ w1,
    const float* __restrict__ w2, const float* __restrict__ w3,
    ushort* __restrict__ wt)
{
    const int mat = blockIdx.z;
    const float* W = mat == 0 ? w0 : mat == 1 ? w1 : mat == 2 ? w2 : w3;
    const int kt0 = blockIdx.x * 64, nt0 = blockIdx.y * 64;
    __shared__ float Ts[64][68];
    const int tid = threadIdx.x;
    {
        const int kl = tid >> 4, nl = (tid & 15) * 4;
#pragma unroll
        for (int rr = 0; rr < 4; ++rr)
            *(float4*)&Ts[kl + rr * 16][nl] =
                *(const float4*)&W[(size_t)(kt0 + kl + rr * 16) * NC_ + nt0 + nl];
    }
    __syncthreads();
    {
        const int n = tid >> 2, k0 = (tid & 3) * 16;
        ushort* dst = &wt[(size_t)mat * 2 * WSQ + (size_t)(nt0 + n) * NC_ + kt0 + k0];
#pragma unroll
        for (int j8 = 0; j8 < 16; j8 += 8) {
            bf16x8 hi8, lo8;
#pragma unroll
            for (int j = 0; j < 8; ++j) {
                float f = Ts[k0 + j8 + j][n];
                ushort h = f2bf(f);
                hi8[j] = (short)h;
                lo8[j] = (short)f2bf(f - bf2f(h));
            }
            *(bf16x8*)&dst[j8] = hi8;
            *(bf16x8*)&dst[WSQ + j8] = lo8;
        }
    }
}

// =====================================================================
// Split-bf16 MFMA GEMM with PRE-SPLIT A: C = A @ W + bias.
// Ahl = [hi NPOS][lo NPOS] bf16, row-major [M][384]. Wt = [plane][n][k].
// 64x64 tile, BK=64; staging is pure b128 copy (no split math).
// =====================================================================
template<int OUT_BF16>
__global__ __launch_bounds__(256) void gemm_mfma2_k(
    const ushort* __restrict__ Ahl, const ushort* __restrict__ Wt,
    const float* __restrict__ bias, void* __restrict__ Cv, int M)
{
    __shared__ __align__(16) ushort At[2][64 * 64];
    const size_t lo_off = (size_t)M * NC_;
    const int m0 = blockIdx.x * 64;
    const int n0 = blockIdx.y * 64;
    const int tid = threadIdx.x;
    const int w = tid >> 6;
    const int lane = tid & 63;
    const int c15 = lane & 15;
    const int lg = lane >> 4;

    f32x4 acc[4];
#pragma unroll
    for (int ct = 0; ct < 4; ++ct) acc[ct] = (f32x4){0.f, 0.f, 0.f, 0.f};

    const int sr = tid >> 2;          // staging row 0..63
    const int sc = (tid & 3) * 16;    // staging col 0,16,32,48

    for (int ks = 0; ks < NC_; ks += 64) {
        const ushort* a0 = &Ahl[(size_t)(m0 + sr) * NC_ + ks + sc];
        bf16x8 h0 = *(const bf16x8*)a0;
        bf16x8 h1 = *(const bf16x8*)(a0 + 8);
        bf16x8 l0 = *(const bf16x8*)(a0 + lo_off);
        bf16x8 l1 = *(const bf16x8*)(a0 + lo_off + 8);
        const int i0 = sr * 64 + (sc ^ ((sr & 7) << 3));
        const int i1 = sr * 64 + ((sc + 8) ^ ((sr & 7) << 3));
        __syncthreads();
        *(bf16x8*)&At[0][i0] = h0;
        *(bf16x8*)&At[0][i1] = h1;
        *(bf16x8*)&At[1][i0] = l0;
        *(bf16x8*)&At[1][i1] = l1;
        __syncthreads();
#pragma unroll
        for (int kc = 0; kc < 64; kc += 32) {
            const int arow = w * 16 + c15;
            const int aidx = arow * 64 + ((kc + lg * 8) ^ ((arow & 7) << 3));
            bf16x8 Ah = *(bf16x8*)&At[0][aidx];
            bf16x8 Al = *(bf16x8*)&At[1][aidx];
            const ushort* wb = &Wt[(size_t)(n0 + c15) * NC_ + ks + kc + lg * 8];
#pragma unroll
            for (int ct = 0; ct < 4; ++ct) {
                bf16x8 Bh = *(const bf16x8*)&wb[(size_t)ct * 16 * NC_];
                bf16x8 Bl = *(const bf16x8*)&wb[WSQ + (size_t)ct * 16 * NC_];
                acc[ct] = __builtin_amdgcn_mfma_f32_16x16x32_bf16(Ah, Bh, acc[ct], 0, 0, 0);
                acc[ct] = __builtin_amdgcn_mfma_f32_16x16x32_bf16(Al, Bh, acc[ct], 0, 0, 0);
                acc[ct] = __builtin_amdgcn_mfma_f32_16x16x32_bf16(Ah, Bl, acc[ct], 0, 0, 0);
            }
        }
    }

#pragma unroll
    for (int ct = 0; ct < 4; ++ct) {
        const int col = n0 + ct * 16 + c15;
        const float bv = bias[col];
#pragma unroll
        for (int r = 0; r < 4; ++r) {
            const size_t row = m0 + w * 16 + lg * 4 + r;
            const float val = acc[ct][r] + bv;
            if constexpr (OUT_BF16)
                ((ushort*)Cv)[row * NC_ + col] = f2bf(val);
            else
                ((float*)Cv)[row * NC_ + col] = val;
        }
    }
}

// =====================================================================
// Conv weight transpose + split (unchanged, validated).
// =====================================================================
__global__ __launch_bounds__(256) void wconv_t_k(
    const float* __restrict__ w, ushort* __restrict__ wt)
{
    const int i = blockIdx.x * 256 + threadIdx.x;
    const int g = i / (9 * GC_ * GC_);
    const int rem = i % (9 * GC_ * GC_);
    const int tap = rem / (GC_ * GC_);
    const int rem2 = rem % (GC_ * GC_);
    const int oc = rem2 >> 6;
    const int ic = rem2 & 63;
    float v = w[(size_t)(tap * GC_ + ic) * NC_ + g * GC_ + oc];
    ushort hi = f2bf(v);
    ushort lo = f2bf(v - bf2f(hi));
    wt[i] = hi;
    wt[WT_ELEMS + i] = lo;
}

// =====================================================================
// Grouped 3x3 conv as split-bf16 implicit-GEMM MFMA (unchanged, validated).
// =====================================================================
__global__ __launch_bounds__(256) void conv_mfma_k(
    const float* __restrict__ q, const ushort* __restrict__ wt,
    const float* __restrict__ bias, float* __restrict__ t)
{
    const int bid = blockIdx.x;
    const int g = bid % NG;
    const int rg = (bid / NG) & 7;
    const int b = bid / (NG * 8);
    const int y0 = rg * 4;

    __shared__ __align__(16) ushort At[2][6 * 34 * 64];

    const int tid = threadIdx.x;
    const int wv = tid >> 6;
    const int lane = tid & 63;
    const int c15 = lane & 15;
    const int lg = lane >> 4;
    const int oc = wv * 16 + c15;

    for (int idx = tid; idx < 6 * 34 * 8; idx += 256) {
        const int cell = idx >> 3;
        const int ch0 = (idx & 7) << 3;
        const int rr = cell / 34, cc = cell % 34;
        const int yy = y0 + rr - 1, xx = cc - 1;
        float v[8];
        if ((unsigned)yy < 32u && (unsigned)xx < 32u) {
            const float* src = &q[(size_t)((b * 32 + yy) * 32 + xx) * NC_ + g * GC_ + ch0];
            *(float4*)&v[0] = *(const float4*)src;
            *(float4*)&v[4] = *(const float4*)(src + 4);
        } else {
#pragma unroll
            for (int j = 0; j < 8; ++j) v[j] = 0.f;
        }
        bf16x8 hi8, lo8;
#pragma unroll
        for (int j = 0; j < 8; ++j) {
            ushort h = f2bf(v[j]);
            hi8[j] = (short)h;
            lo8[j] = (short)f2bf(v[j] - bf2f(h));
        }
        const int wi = cell * 64 + (ch0 ^ ((cc & 7) << 3));
        *(bf16x8*)&At[0][wi] = hi8;
        *(bf16x8*)&At[1][wi] = lo8;
    }

    const float bval = bias[g * GC_ + oc];
    f32x4 acc[8];
#pragma unroll
    for (int m = 0; m < 8; ++m) acc[m] = (f32x4){bval, bval, bval, bval};

    __syncthreads();

#pragma unroll
    for (int tap = 0; tap < 9; ++tap) {
        const int kh = tap / 3, kw = tap % 3;
        const ushort* wb = &wt[(size_t)((g * 9 + tap) * GC_ + oc) * GC_ + lg * 8];
        bf16x8 Bh0 = *(const bf16x8*)&wb[0];
        bf16x8 Bh1 = *(const bf16x8*)&wb[32];
        bf16x8 Bl0 = *(const bf16x8*)&wb[WT_ELEMS];
        bf16x8 Bl1 = *(const bf16x8*)&wb[WT_ELEMS + 32];
#pragma unroll
        for (int m = 0; m < 8; ++m) {
            const int rr = (m >> 1) + kh;
            const int cc = (m & 1) * 16 + kw + c15;
            const int base = (rr * 34 + cc) * 64;
            const int sw = (cc & 7) << 3;
            bf16x8 Ah0 = *(const bf16x8*)&At[0][base + ((lg * 8) ^ sw)];
            bf16x8 Ah1 = *(const bf16x8*)&At[0][base + ((32 + lg * 8) ^ sw)];
            bf16x8 Al0 = *(const bf16x8*)&At[1][base + ((lg * 8) ^ sw)];
            bf16x8 Al1 = *(const bf16x8*)&At[1][base + ((32 + lg * 8) ^ sw)];
            acc[m] = __builtin_amdgcn_mfma_f32_16x16x32_bf16(Ah0, Bh0, acc[m], 0, 0, 0);
            acc[m] = __builtin_amdgcn_mfma_f32_16x16x32_bf16(Ah1, Bh1, acc[m], 0, 0, 0);
            acc[m] = __builtin_amdgcn_mfma_f32_16x16x32_bf16(Al0, Bh0, acc[m], 0, 0, 0);
            acc[m] = __builtin_amdgcn_mfma_f32_16x16x32_bf16(Al1, Bh1, acc[m], 0, 0, 0);
            acc[m] = __builtin_amdgcn_mfma_f32_16x16x32_bf16(Ah0, Bl0, acc[m], 0, 0, 0);
            acc[m] = __builtin_amdgcn_mfma_f32_16x16x32_bf16(Ah1, Bl1, acc[m], 0, 0, 0);
        }
    }

#pragma unroll
    for (int m = 0; m < 8; ++m) {
        const int y = y0 + (m >> 1);
#pragma unroll
        for (int r = 0; r < 4; ++r) {
            const int x = (m & 1) * 16 + lg * 4 + r;
            t[(size_t)((b * 32 + y) * 32 + x) * NC_ + g * GC_ + oc] = acc[m][r];
        }
    }
}

// =====================================================================
// LayerNorm(384) + erf-GELU + per-group 64->2 proj + tanh*16 + ref grid.
// =====================================================================
__global__ __launch_bounds__(384) void ln_gelu_off_k(
    const float* __restrict__ t, const float* __restrict__ ln_g,
    const float* __restrict__ ln_b, const float* __restrict__ w_offp,
    float* __restrict__ warp)
{
    const int p = blockIdx.x;
    const int c = threadIdx.x;
    const int lane = c & 63;
    const int wv = c >> 6;

    __shared__ float red[8];
    float v = t[(size_t)p * NC_ + c];

    float s = v;
#pragma unroll
    for (int o = 32; o > 0; o >>= 1) s += __shfl_down(s, o, 64);
    if (lane == 0) red[wv] = s;
    __syncthreads();
    float mu = (red[0] + red[1] + red[2] + red[3] + red[4] + red[5]) * (1.f / 384.f);
    __syncthreads();

    float d = v - mu;
    s = d * d;
#pragma unroll
    for (int o = 32; o > 0; o >>= 1) s += __shfl_down(s, o, 64);
    if (lane == 0) red[wv] = s;
    __syncthreads();
    float var = (red[0] + red[1] + red[2] + red[3] + red[4] + red[5]) * (1.f / 384.f);

    float nv = (v - mu) * rsqrtf(var + 1e-3f) * ln_g[c] + ln_b[c];
    float gv = 0.5f * nv * (1.0f + erff(nv * 0.70710678118654752440f));

    float s0 = gv * w_offp[lane * 2 + 0];
    float s1 = gv * w_offp[lane * 2 + 1];
#pragma unroll
    for (int o = 32; o > 0; o >>= 1) {
        s0 += __shfl_down(s0, o, 64);
        s1 += __shfl_down(s1, o, 64);
    }
    if (lane == 0) {
        int b = p >> 10, ij = p & 1023;
        int i = ij >> 5, j = ij & 31;
        float off0 = tanhf(s0) * 16.0f;
        float off1 = tanhf(s1) * 16.0f;
        float px = off1 + (float)i;
        float py = off0 + (float)j;
        int bg = b * NG + wv;
        warp[((size_t)bg * NQ + ij) * 2 + 0] = px;
        warp[((size_t)bg * NQ + ij) * 2 + 1] = py;
    }
}

// =====================================================================
// Bilinear sampling with zero border -> writes hi/lo bf16 directly.
// =====================================================================
__device__ inline float4 tap_load(const float* __restrict__ x, int b, int g,
                                  int yp, int xp, int ic4)
{
    int r = yp - 1, c = xp - 1;
    if ((unsigned)r < 32u && (unsigned)c < 32u)
        return *(const float4*)&x[(size_t)(((b * 32 + r) * 32 + c)) * NC_ + g * GC_ + ic4];
    return make_float4(0.f, 0.f, 0.f, 0.f);
}

__global__ __launch_bounds__(256) void sample_kk(
    const float* __restrict__ x, const float* __restrict__ warp,
    ushort* __restrict__ xs_hl)
{
    const int gidx = blockIdx.x * 256 + threadIdx.x;
    const int ic4 = (gidx & 15) * 4;
    const int qq = (gidx >> 4) & 1023;
    const int bg = gidx >> 14;
    const int b = bg / NG, g = bg % NG;

    const float wx = warp[((size_t)bg * NQ + qq) * 2 + 0];
    const float wy = warp[((size_t)bg * NQ + qq) * 2 + 1];
    const float xq = wx + 1.0f, yq = wy + 1.0f;
    float x0 = fminf(fmaxf(floorf(xq), 0.f), 32.f);
    float y0 = fminf(fmaxf(floorf(yq), 0.f), 32.f);
    float ax = fminf(fmaxf(xq - x0, 0.f), 1.f);
    float ay = fminf(fmaxf(yq - y0, 0.f), 1.f);
    int xi = (int)x0, yi = (int)y0;

    float4 tl = tap_load(x, b, g, yi,     xi,     ic4);
    float4 tr = tap_load(x, b, g, yi,     xi + 1, ic4);
    float4 bl = tap_load(x, b, g, yi + 1, xi,     ic4);
    float4 br = tap_load(x, b, g, yi + 1, xi + 1, ic4);

    float4 top, bot, r;
    top.x = tl.x + ax * (tr.x - tl.x); top.y = tl.y + ax * (tr.y - tl.y);
    top.z = tl.z + ax * (tr.z - tl.z); top.w = tl.w + ax * (tr.w - tl.w);
    bot.x = bl.x + ax * (br.x - bl.x); bot.y = bl.y + ax * (br.y - bl.y);
    bot.z = bl.z + ax * (br.z - bl.z); bot.w = bl.w + ax * (br.w - bl.w);
    r.x = top.x + ay * (bot.x - top.x); r.y = top.y + ay * (bot.y - top.y);
    r.z = top.z + ay * (bot.z - top.z); r.w = top.w + ay * (bot.w - top.w);

    ushort4 hi, lo;
    hi.x = f2bf(r.x); lo.x = f2bf(r.x - bf2f(hi.x));
    hi.y = f2bf(r.y); lo.y = f2bf(r.y - bf2f(hi.y));
    hi.z = f2bf(r.z); lo.z = f2bf(r.z - bf2f(hi.z));
    hi.w = f2bf(r.w); lo.w = f2bf(r.w - bf2f(hi.w));
    const size_t oidx = ((size_t)b * NQ + qq) * NC_ + g * GC_ + ic4;
    *(ushort4*)&xs_hl[oidx] = hi;
    *(ushort4*)&xs_hl[NPOS_ELEMS + oidx] = lo;
}

// =====================================================================
// V transpose: vb[b][n][384] bf16 (head slice) -> vt[b][h][c][n] bf16.
// =====================================================================
__global__ __launch_bounds__(256) void vtrans_k(
    const ushort* __restrict__ vb, ushort* __restrict__ vt)
{
    const int bid = blockIdx.x;
    const int nt = bid & 15;
    const int h = (bid >> 4) % NH;
    const int b = bid / (16 * NH);
    const int n0 = nt * 64;
    __shared__ __align__(16) ushort Ls[32][72];
    const int tid = threadIdx.x;
    {
        const int n = tid >> 2, c0 = (tid & 3) * 8;
        bf16x8 v = *(const bf16x8*)&vb[(size_t)(b * NQ + n0 + n) * NC_ + h * HC_ + c0];
#pragma unroll
        for (int j = 0; j < 8; ++j) Ls[c0 + j][n] = (ushort)v[j];
    }
    __syncthreads();
    {
        const int c = tid >> 3, n1 = (tid & 7) * 8;
        bf16x8 o = *(const bf16x8*)&Ls[c][n1];
        *(bf16x8*)&vt[(size_t)((b * NH + h) * HC_ + c) * NQ + n0 + n1] = o;
    }
}

// =====================================================================
// MFMA flash attention, swapped-operand softmax:
// S computed as mfma(K,Q) so each lane owns a full 16-value S-slice of ONE
// query -> softmax reduce = 15 in-lane ops + 2 shfl_xor (was 32 shfls).
// K prefetched one tile ahead; V issued early (covered by softmax).
// Output written directly as hi/lo bf16 (pre-split for the O-projection).
// =====================================================================
__global__ __launch_bounds__(256) void attn_mfma2_k(
    const float* __restrict__ q, const ushort* __restrict__ kb,
    const ushort* __restrict__ vt, ushort* __restrict__ ohl)
{
    __shared__ __align__(16) ushort Pl[4][1024];   // per-wave [16q][64k], swizzled

    const int mt = blockIdx.x;
    const int bh = blockIdx.y;
    const int b = bh / NH, h = bh % NH;
    const int tid = threadIdx.x;
    const int w = tid >> 6;
    const int lane = tid & 63;
    const int c15 = lane & 15;
    const int lg = lane >> 4;

    const float scale = 0.17677669529663687f;

    // Q fragment (B operand): Q[query=c15][k=lg*8+i]
    bf16x8 qf;
    {
        const float* qp = &q[((size_t)b * NQ + mt * 64 + w * 16 + c15) * NC_ + h * HC_ + lg * 8];
        float tmp[8];
        *(float4*)&tmp[0] = *(const float4*)qp;
        *(float4*)&tmp[4] = *(const float4*)(qp + 4);
#pragma unroll
        for (int i = 0; i < 8; ++i) tmp[i] *= scale;
        qf = pack8(tmp);
    }

    f32x4 oacc[2];
    oacc[0] = (f32x4){0.f, 0.f, 0.f, 0.f};
    oacc[1] = (f32x4){0.f, 0.f, 0.f, 0.f};
    float m_i = -INFINITY, l_i = 0.f;

    const ushort* kbase = &kb[((size_t)b * NQ + c15) * NC_ + h * HC_ + lg * 8];
    const size_t vbase = (size_t)((b * NH + h) * HC_) * NQ + lg * 8;
    const int sw = (c15 & 7) << 3;

    // prefetch K tile 0 (A operand: K[key=c15(+16kt)][k=lg*8+i])
    bf16x8 kf[4], kn[4];
#pragma unroll
    for (int kt = 0; kt < 4; ++kt)
        kf[kt] = *(const bf16x8*)(kbase + (size_t)(kt * 16) * NC_);

    for (int t = 0; t < 16; ++t) {
        const int n0 = t * 64;
        // V frags for current tile (independent; covered by QK^T+softmax)
        bf16x8 vf[4];
#pragma unroll
        for (int kblk = 0; kblk < 2; ++kblk)
#pragma unroll
            for (int ct = 0; ct < 2; ++ct)
                vf[kblk * 2 + ct] = *(const bf16x8*)&vt[vbase + (size_t)(ct * 16 + c15) * NQ + n0 + kblk * 32];
        // prefetch next K tile
        if (t < 15) {
#pragma unroll
            for (int kt = 0; kt < 4; ++kt)
                kn[kt] = *(const bf16x8*)(kbase + (size_t)(n0 + 64 + kt * 16) * NC_);
        }

        // S = K.Q^T: sacc[kt][r] = S[key=n0+kt*16+lg*4+r][query=c15]
        f32x4 sacc[4];
        const f32x4 z = (f32x4){0.f, 0.f, 0.f, 0.f};
#pragma unroll
        for (int kt = 0; kt < 4; ++kt)
            sacc[kt] = __builtin_amdgcn_mfma_f32_16x16x32_bf16(kf[kt], qf, z, 0, 0, 0);

        // in-lane softmax over this lane's 16 keys + cross-lg combine
        float mx = -INFINITY;
#pragma unroll
        for (int kt = 0; kt < 4; ++kt)
#pragma unroll
            for (int r = 0; r < 4; ++r) mx = fmaxf(mx, sacc[kt][r]);
        mx = fmaxf(mx, __shfl_xor(mx, 16, 64));
        mx = fmaxf(mx, __shfl_xor(mx, 32, 64));
        float mn = fmaxf(m_i, mx);
        float al = __expf(m_i - mn);
        m_i = mn;

        float p[4][4];
        float rs = 0.f;
#pragma unroll
        for (int kt = 0; kt < 4; ++kt)
#pragma unroll
            for (int r = 0; r < 4; ++r) {
                p[kt][r] = __expf(sacc[kt][r] - mn);
                rs += p[kt][r];
            }
        rs += __shfl_xor(rs, 16, 64);
        rs += __shfl_xor(rs, 32, 64);
        l_i = l_i * al + rs;

        // P -> per-wave LDS: [query=c15][key], 4 consecutive keys per b64 write
#pragma unroll
        for (int kt = 0; kt < 4; ++kt) {
            ushort4 pk;
            pk.x = f2bf(p[kt][0]);
            pk.y = f2bf(p[kt][1]);
            pk.z = f2bf(p[kt][2]);
            pk.w = f2bf(p[kt][3]);
            *(ushort4*)&Pl[w][c15 * 64 + ((kt * 16 + lg * 4) ^ sw)] = pk;
        }

        // alpha broadcast to O layout (query = lg*4+r) + rescale
        float a0 = __shfl(al, lg * 4 + 0, 64);
        float a1 = __shfl(al, lg * 4 + 1, 64);
        float a2 = __shfl(al, lg * 4 + 2, 64);
        float a3 = __shfl(al, lg * 4 + 3, 64);
#pragma unroll
        for (int ct = 0; ct < 2; ++ct) {
            oacc[ct][0] *= a0; oacc[ct][1] *= a1;
            oacc[ct][2] *= a2; oacc[ct][3] *= a3;
        }

        // O += P.V  (A-frag: P[query=c15][key=kblk*32+lg*8+i])
#pragma unroll
        for (int kblk = 0; kblk < 2; ++kblk) {
            bf16x8 pf = *(bf16x8*)&Pl[w][c15 * 64 + ((kblk * 32 + lg * 8) ^ sw)];
            oacc[0] = __builtin_amdgcn_mfma_f32_16x16x32_bf16(pf, vf[kblk * 2 + 0], oacc[0], 0, 0, 0);
            oacc[1] = __builtin_amdgcn_mfma_f32_16x16x32_bf16(pf, vf[kblk * 2 + 1], oacc[1], 0, 0, 0);
        }

        if (t < 15) {
#pragma unroll
            for (int kt = 0; kt < 4; ++kt) kf[kt] = kn[kt];
        }
    }

    // broadcast 1/l to O layout and store hi/lo bf16
    float linv = 1.f / l_i;
    float li[4];
    li[0] = __shfl(linv, lg * 4 + 0, 64);
    li[1] = __shfl(linv, lg * 4 + 1, 64);
    li[2] = __shfl(linv, lg * 4 + 2, 64);
    li[3] = __shfl(linv, lg * 4 + 3, 64);
#pragma unroll
    for (int r = 0; r < 4; ++r) {
        const size_t row = (size_t)b * NQ + mt * 64 + w * 16 + lg * 4 + r;
#pragma unroll
        for (int ct = 0; ct < 2; ++ct) {
            const float val = oacc[ct][r] * li[r];
            const ushort hh = f2bf(val);
            const size_t idx = row * NC_ + h * HC_ + ct * 16 + c15;
            ohl[idx] = hh;
            ohl[NPOS_ELEMS + idx] = f2bf(val - bf2f(hh));
        }
    }
}

// =====================================================================
// Launch. ws floats (NPOS = 3,145,728):
// slot0: q fp32 | slot1: t fp32 | slot2: xs hi/lo, later attn-out hi/lo
// slot3: x hi/lo (early), later kb16|vb16 | slot4: vt | wtc | wtsq
// slot5 (at 5*NPOS): warp coords
// =====================================================================
extern "C" void kernel_launch(void* const* d_in, const int* in_sizes, int n_in,
                              void* d_out, int out_size, void* d_ws, size_t ws_size,
                              hipStream_t stream)
{
    const float* x      = (const float*)d_in[0];
    const float* w_q    = (const float*)d_in[1];
    const float* b_q    = (const float*)d_in[2];
    const float* w_off0 = (const float*)d_in[3];
    const float* b_off0 = (const float*)d_in[4];
    const float* ln_g   = (const float*)d_in[5];
    const float* ln_b   = (const float*)d_in[6];
    const float* w_offp = (const float*)d_in[7];
    const float* w_k    = (const float*)d_in[8];
    const float* b_k    = (const float*)d_in[9];
    const float* w_v    = (const float*)d_in[10];
    const float* b_v    = (const float*)d_in[11];
    const float* w_o    = (const float*)d_in[12];
    const float* b_o    = (const float*)d_in[13];

    float* ws = (float*)d_ws;
    float*  q     = ws;
    float*  t     = ws + (size_t)NPOS_ELEMS;
    ushort* xs_hl = (ushort*)(ws + (size_t)2 * NPOS_ELEMS);  // also attn-out hi/lo
    ushort* xhl   = (ushort*)(ws + (size_t)3 * NPOS_ELEMS);  // dead before kb16
    ushort* kb16  = (ushort*)(ws + (size_t)3 * NPOS_ELEMS);
    ushort* vb16  = kb16 + NPOS_ELEMS;
    ushort* vt    = (ushort*)(ws + (size_t)4 * NPOS_ELEMS);
    ushort* wtc   = vt + NPOS_ELEMS;
    ushort* wtsq  = wtc + 2 * WT_ELEMS;
    float*  wp    = ws + (size_t)5 * NPOS_ELEMS;

    ushort* wtq = wtsq;
    ushort* wtk = wtsq + 2 * WSQ;
    ushort* wtv = wtsq + 4 * WSQ;
    ushort* wto = wtsq + 6 * WSQ;

    const int M = BB * NQ;   // 8192

    wconv_t_k<<<WT_ELEMS / 256, 256, 0, stream>>>(w_off0, wtc);
    wsplit_k<<<dim3(6, 6, 4), 256, 0, stream>>>(w_q, w_k, w_v, w_o, wtsq);
    split_k<<<NPOS_ELEMS / 1024, 256, 0, stream>>>(x, xhl, NPOS_ELEMS);
    gemm_mfma2_k<0><<<dim3(M / 64, 6), 256, 0, stream>>>(xhl, wtq, b_q, (void*)q, M);
    conv_mfma_k<<<BB * 8 * NG, 256, 0, stream>>>(q, wtc, b_off0, t);
    ln_gelu_off_k<<<M, 384, 0, stream>>>(t, ln_g, ln_b, w_offp, wp);
    sample_kk<<<(BB * NG * NQ * 16) / 256, 256, 0, stream>>>(x, wp, xs_hl);
    gemm_mfma2_k<1><<<dim3(M / 64, 6), 256, 0, stream>>>(xs_hl, wtk, b_k, (void*)kb16, M);
    gemm_mfma2_k<1><<<dim3(M / 64, 6), 256, 0, stream>>>(xs_hl, wtv, b_v, (void*)vb16, M);
    vtrans_k<<<BB * NH * 16, 256, 0, stream>>>(vb16, vt);
    attn_mfma2_k<<<dim3(NQ / 64, BB * NH), 256, 0, stream>>>(q, kb16, vt, xs_hl);
    gemm_mfma2_k<0><<<dim3(M / 64, 6), 256, 0, stream>>>(xs_hl, wto, b_o, d_out, M);
}